// Round 7
// baseline (550.450 us; speedup 1.0000x reference)
//
#include <hip/hip_runtime.h>
#include <math.h>

#define N_NODES 20000
#define N_EDGES 50000
#define NB      1024
#define IND     32
#define HDIM    64

#define CHUNK    192
#define NCHUNK   ((N_EDGES + CHUNK - 1) / CHUNK)   // 261
#define VPSTRIDE 193

typedef __attribute__((ext_vector_type(8))) short bf16x8;
typedef __attribute__((ext_vector_type(4))) float f32x4;

static inline size_t align_up(size_t x, size_t a) { return (x + a - 1) & ~(a - 1); }

__device__ __forceinline__ float sigmoidf_(float x) {
    return 1.0f / (1.0f + __expf(-x));
}
__device__ __forceinline__ float tanhf_(float x) {
    float xc = fminf(fmaxf(x, -15.0f), 15.0f);
    float e = __expf(2.0f * xc);
    return (e - 1.0f) / (e + 1.0f);
}
__device__ __forceinline__ unsigned pk2(float p0, float p1) {
    unsigned u0 = __float_as_uint(p0) + 0x8000u;
    unsigned u1 = __float_as_uint(p1) + 0x8000u;
    return __builtin_amdgcn_perm(u1, u0, 0x07060302u);
}
__device__ __forceinline__ unsigned bf1(float v) {
    return (__float_as_uint(v) + 0x8000u) >> 16;
}

// ---- mega-prep: We2b permute + wsplit + LSTM transposes + offsets + node_init +
//      edge_feat + edge degree count (deg pre-zeroed by memset BEFORE this kernel) ----
// grid = 1040 + 112 + 128 + 64 + 5 (=1349) + 5000 (node) + 12500 (edge) + 196 (count) = 19045
__global__ void k_prep(const float* __restrict__ We2, const float* __restrict__ be2,
                       short* __restrict__ We2b,
                       const float* __restrict__ Wroot, const float* __restrict__ gwhh,
                       const float* __restrict__ gwih,
                       short* __restrict__ WB1h, short* __restrict__ WB1l,
                       short* __restrict__ WB2h, short* __restrict__ WB2l,
                       const float* __restrict__ lwih, const float* __restrict__ lwhh,
                       float* __restrict__ lwihT, float* __restrict__ lwhhT,
                       const int* __restrict__ batch, int* __restrict__ offs,
                       const float* __restrict__ x, const float* __restrict__ W0,
                       const float* __restrict__ b0, float* __restrict__ hbuf,
                       const float* __restrict__ ea, const float* __restrict__ We1,
                       const float* __restrict__ be1, float* __restrict__ re,
                       const int* __restrict__ ei, int* __restrict__ deg) {
    int bid = blockIdx.x, tid = threadIdx.x;
    if (bid < 1040) {
        int idx = bid * 256 + tid;                 // 0 .. 65*4096-1
        int s = idx >> 12;
        int col = idx & 4095;
        int k = col >> 6, o = col & 63;
        float val = (s < 64) ? We2[k * 4096 + s * 64 + o] : be2[k * 64 + o];
        int dst = s * 4096 + (((o >> 4) * 128 + (k >> 5) * 64 + ((k >> 3) & 3) * 16 + (o & 15)) << 3) + (k & 7);
        We2b[dst] = (short)bf1(val);
    } else if (bid < 1152) {
        int idx = (bid - 1040) * 256 + tid;
        if (idx < 28672) {
            bool b1 = idx < 16384;
            int li = b1 ? idx : idx - 16384;
            int j = li & 7, lane = (li >> 3) & 63, c = (li >> 9) & 1, otile = li >> 10;
            int k = c * 32 + (lane >> 4) * 8 + j;
            int o = otile * 16 + (lane & 15);
            float val;
            if (b1) val = (o < 64) ? Wroot[k * 64 + o] : gwhh[(o - 64) * 64 + k];
            else    val = gwih[o * 64 + k];
            unsigned hs = bf1(val);
            float lo = val - __uint_as_float(hs << 16);
            unsigned ls = bf1(lo);
            if (b1) { WB1h[li] = (short)hs; WB1l[li] = (short)ls; }
            else    { WB2h[li] = (short)hs; WB2l[li] = (short)ls; }
        }
    } else if (bid < 1280) {
        int idx = (bid - 1152) * 256 + tid;        // < 32768 : lwihT[i*256+j] = lwih[j*128+i]
        int i = idx >> 8, j = idx & 255;
        lwihT[idx] = lwih[j * 128 + i];
    } else if (bid < 1344) {
        int idx = (bid - 1280) * 256 + tid;        // < 16384 : lwhhT[i*256+j] = lwhh[j*64+i]
        int i = idx >> 8, j = idx & 255;
        lwhhT[idx] = lwhh[j * 64 + i];
    } else if (bid < 1349) {
        int i = (bid - 1344) * 256 + tid;
        if (i <= NB) {
            int lo = 0, hi = N_NODES;
            while (lo < hi) { int mid = (lo + hi) >> 1; if (batch[mid] < i) lo = mid + 1; else hi = mid; }
            offs[i] = lo;
        }
    } else if (bid < 6349) {
        int w = tid >> 6, j = tid & 63;
        int n = (bid - 1349) * 4 + w;
        float acc = b0[j];
        const float* xr = x + n * IND;
#pragma unroll
        for (int i = 0; i < IND; ++i) acc = fmaf(xr[i], W0[i * 64 + j], acc);
        hbuf[n * 64 + j] = fmaxf(acc, 0.0f);
    } else if (bid < 18849) {
        int w = tid >> 6, j = tid & 63;
        int e = (bid - 6349) * 4 + w;
        if (e < N_EDGES) {
            float acc = be1[j];
            const float* er = ea + e * 6;
#pragma unroll
            for (int i = 0; i < 6; ++i) acc = fmaf(er[i], We1[i * 64 + j], acc);
            re[e * 64 + j] = fmaxf(acc, 0.0f);
        }
    } else {
        int e = (bid - 18849) * 256 + tid;
        if (e < N_EDGES) atomicAdd(&deg[ei[N_EDGES + e]], 1);
    }
}

__global__ void k_scan(const int* __restrict__ deg, int* __restrict__ rowptr, int* __restrict__ cursor) {
    __shared__ int s_w[16];
    int t = threadIdx.x;
    int base = t * 20;
    int v[20]; int s = 0;
#pragma unroll
    for (int i = 0; i < 20; ++i) {
        int idx = base + i;
        v[i] = (idx < N_NODES) ? deg[idx] : 0;
        s += v[i];
    }
    int lane = t & 63, w = t >> 6;
    int inc = s;
#pragma unroll
    for (int off = 1; off < 64; off <<= 1) {
        int o = __shfl_up(inc, off);
        if (lane >= off) inc += o;
    }
    if (lane == 63) s_w[w] = inc;
    __syncthreads();
    if (w == 0 && lane < 16) {
        int x = s_w[lane];
        int xs = x;
#pragma unroll
        for (int off = 1; off < 16; off <<= 1) {
            int o = __shfl_up(xs, off);
            if (lane >= off) xs += o;
        }
        s_w[lane] = xs - x;
    }
    __syncthreads();
    int run = s_w[w] + (inc - s);
#pragma unroll
    for (int i = 0; i < 20; ++i) {
        int idx = base + i;
        if (idx < N_NODES) { rowptr[idx] = run; cursor[idx] = run; }
        else if (idx == N_NODES) rowptr[idx] = run;
        run += v[i];
    }
}

__global__ void k_fill(const int* __restrict__ ei, int* __restrict__ cursor, int* __restrict__ perm) {
    int e = blockIdx.x * 256 + threadIdx.x;
    if (e < N_EDGES) {
        int pos = atomicAdd(&cursor[ei[N_EDGES + e]], 1);
        perm[pos] = e;
    }
}

// msg kernel — LDS-resident W-slice, 4 o-quarters x 64 edge-blocks = 256 blocks (1/CU):
//   Per-CU L2 delivery caps at ~16 B/cyc (R0-R6 evidence); R2's 46.6us = its 1.6MB/CU W
//   stream at that cap. Here each block loads its o-quarter W-slice (64 slabs x 2KB,
//   contiguous in the We2b permute) into LDS ONCE (128 KB), then loops ~4 chunks of 192
//   edges with a PURE LDS+MFMA inner loop — no global traffic, no barriers, compiler-
//   scheduled lgkmcnt (the regime that works). v is staged as packed-bf16 pairs
//   vpk[32][193] (24 KB, stride-193 kills write bank conflicts). Bias slab (64) lives in
//   2 register frags; its B-operand is vpk rows directly. Stores are direct dwordx4.
//   Total W traffic: 407 MB -> 33 MB; per-CU global reads ~560 KB.
__launch_bounds__(256, 1)
__global__ void k_msg_mfma(const float* __restrict__ hbuf, const float* __restrict__ reb,
                           const short* __restrict__ We2b, const int* __restrict__ ei,
                           float* __restrict__ msg) {
    __shared__ int4 sW[64 * 128];             // 128 KB: 64 slabs, o-quarter slice each
    __shared__ unsigned vpk[32 * VPSTRIDE];   // 24.1 KB: v as bf16 pairs [s2][e]
    int tid = threadIdx.x;
    int lane = tid & 63, w = tid >> 6;
    int l15 = lane & 15, lhi = lane >> 4;
    int q = blockIdx.x & 3;                   // o-quarter
    int jb = blockIdx.x >> 2;                 // 0..63
    int webase = w * 48;                      // wave's 48 edges (3 m-tiles)
    int erow = tid >> 4, c4 = tid & 15;       // v-stage decomposition

    const int4* gW = (const int4*)We2b;       // slab stride = 512 int4 (8 KB)
    union U { int4 i4; bf16x8 v; };

    // bias slab (64) frags, register-resident for the whole kernel
    U bW0, bW1;
    bW0.i4 = gW[64 * 512 + q * 128 + lane];
    bW1.i4 = gW[64 * 512 + q * 128 + 64 + lane];

    // W-slice DMA: wave w loads slabs 4r+w; quarter slice is contiguous 2 KB at +q*128 int4
    for (int r = 0; r < 16; ++r) {
        int s = r * 4 + w;
        const int4* src = gW + (size_t)s * 512 + q * 128;
        __builtin_amdgcn_global_load_lds(
            (const __attribute__((address_space(1))) int4*)(src + lane),
            (__attribute__((address_space(3))) int4*)&sW[s * 128], 16, 0, 0);
        __builtin_amdgcn_global_load_lds(
            (const __attribute__((address_space(1))) int4*)(src + 64 + lane),
            (__attribute__((address_space(3))) int4*)&sW[s * 128 + 64], 16, 0, 0);
    }

    float4 vr[12];
    U a_re[3][2];

    auto stage_load = [&](int cidx) {
#pragma unroll
        for (int k = 0; k < 12; ++k) {
            int ge = cidx * CHUNK + erow + k * 16;
            if (ge < N_EDGES)
                vr[k] = *(const float4*)(hbuf + (size_t)ei[ge] * 64 + c4 * 4);
            else
                vr[k] = make_float4(0.f, 0.f, 0.f, 0.f);
        }
    };
    auto pack_write = [&]() {
#pragma unroll
        for (int k = 0; k < 12; ++k) {
            int el = erow + k * 16;
            vpk[(c4 * 2 + 0) * VPSTRIDE + el] = pk2(vr[k].x, vr[k].y);
            vpk[(c4 * 2 + 1) * VPSTRIDE + el] = pk2(vr[k].z, vr[k].w);
        }
    };
    auto pack_a_re = [&](int cidx) {
#pragma unroll
        for (int m = 0; m < 3; ++m) {
            int ge = cidx * CHUNK + webase + m * 16 + l15;
            if (ge < N_EDGES) {
                const float* rp = reb + (size_t)ge * 64 + lhi * 8;
                float4 x0 = *(const float4*)(rp);
                float4 x1 = *(const float4*)(rp + 4);
                float4 y0 = *(const float4*)(rp + 32);
                float4 y1 = *(const float4*)(rp + 36);
                a_re[m][0].i4 = make_int4(pk2(x0.x, x0.y), pk2(x0.z, x0.w), pk2(x1.x, x1.y), pk2(x1.z, x1.w));
                a_re[m][1].i4 = make_int4(pk2(y0.x, y0.y), pk2(y0.z, y0.w), pk2(y1.x, y1.y), pk2(y1.z, y1.w));
            } else {
                a_re[m][0].i4 = make_int4(0, 0, 0, 0);
                a_re[m][1].i4 = make_int4(0, 0, 0, 0);
            }
        }
    };

    stage_load(jb);
    pack_a_re(jb);
    __syncthreads();          // drains W DMA + vr/a_re loads (syncthreads = vmcnt0+barrier)
    pack_write();
    __syncthreads();          // vpk(jb) visible

    const f32x4 zero4 = {0.f, 0.f, 0.f, 0.f};
    int c = jb;
    while (true) {
        f32x4 macc[3];
#pragma unroll
        for (int m = 0; m < 3; ++m) macc[m] = zero4;

#pragma unroll 4
        for (int sp = 0; sp < 32; ++sp) {
            U Fa0, Fb0, Fa1, Fb1;
            Fa0.i4 = sW[(2 * sp) * 128 + lane];
            Fb0.i4 = sW[(2 * sp) * 128 + 64 + lane];
            Fa1.i4 = sW[(2 * sp + 1) * 128 + lane];
            Fb1.i4 = sW[(2 * sp + 1) * 128 + 64 + lane];
            unsigned uvm[3];
#pragma unroll
            for (int m = 0; m < 3; ++m) uvm[m] = vpk[sp * VPSTRIDE + webase + m * 16 + l15];
#pragma unroll
            for (int m = 0; m < 3; ++m) {
                float fe = __uint_as_float(uvm[m] << 16);
                float fo = __uint_as_float(uvm[m] & 0xffff0000u);
                f32x4 t0 = __builtin_amdgcn_mfma_f32_16x16x32_bf16(Fa0.v, a_re[m][0].v, zero4, 0, 0, 0);
                t0 = __builtin_amdgcn_mfma_f32_16x16x32_bf16(Fb0.v, a_re[m][1].v, t0, 0, 0, 0);
                macc[m][0] = fmaf(fe, t0[0], macc[m][0]);
                macc[m][1] = fmaf(fe, t0[1], macc[m][1]);
                macc[m][2] = fmaf(fe, t0[2], macc[m][2]);
                macc[m][3] = fmaf(fe, t0[3], macc[m][3]);
                f32x4 t1 = __builtin_amdgcn_mfma_f32_16x16x32_bf16(Fa1.v, a_re[m][0].v, zero4, 0, 0, 0);
                t1 = __builtin_amdgcn_mfma_f32_16x16x32_bf16(Fb1.v, a_re[m][1].v, t1, 0, 0, 0);
                macc[m][0] = fmaf(fo, t1[0], macc[m][0]);
                macc[m][1] = fmaf(fo, t1[1], macc[m][1]);
                macc[m][2] = fmaf(fo, t1[2], macc[m][2]);
                macc[m][3] = fmaf(fo, t1[3], macc[m][3]);
            }
        }

        // bias: msg += v @ be2 (B operand = vpk rows as bf16x8 k-frags)
#pragma unroll
        for (int m = 0; m < 3; ++m) {
            int e = webase + m * 16 + l15;
            U vb0, vb1;
            vb0.i4 = make_int4((int)vpk[(lhi * 4 + 0) * VPSTRIDE + e], (int)vpk[(lhi * 4 + 1) * VPSTRIDE + e],
                               (int)vpk[(lhi * 4 + 2) * VPSTRIDE + e], (int)vpk[(lhi * 4 + 3) * VPSTRIDE + e]);
            vb1.i4 = make_int4((int)vpk[(16 + lhi * 4 + 0) * VPSTRIDE + e], (int)vpk[(16 + lhi * 4 + 1) * VPSTRIDE + e],
                               (int)vpk[(16 + lhi * 4 + 2) * VPSTRIDE + e], (int)vpk[(16 + lhi * 4 + 3) * VPSTRIDE + e]);
            macc[m] = __builtin_amdgcn_mfma_f32_16x16x32_bf16(bW0.v, vb0.v, macc[m], 0, 0, 0);
            macc[m] = __builtin_amdgcn_mfma_f32_16x16x32_bf16(bW1.v, vb1.v, macc[m], 0, 0, 0);
        }

        // store: lane holds o = q*16 + lhi*4 + 0..3 for edge e = l15 of m-tile -> dwordx4
#pragma unroll
        for (int m = 0; m < 3; ++m) {
            int ge = c * CHUNK + webase + m * 16 + l15;
            if (ge < N_EDGES)
                *(float4*)&msg[(size_t)ge * 64 + q * 16 + lhi * 4] =
                    make_float4(macc[m][0], macc[m][1], macc[m][2], macc[m][3]);
        }

        int c2 = c + 64;
        if (c2 >= NCHUNK) break;
        __syncthreads();      // all waves done reading vpk(c)
        stage_load(c2);
        pack_a_re(c2);
        pack_write();
        __syncthreads();      // vpk(c2) visible
        c = c2;
    }
}

// MFMA node update: conv + GRU with split-bf16 weights. 32 nodes / block (625 blocks).
__launch_bounds__(256, 4)
__global__ void k_node_update(float* __restrict__ hbuf, const float* __restrict__ msg,
                              const int* __restrict__ rowptr, const int* __restrict__ perm,
                              const short* __restrict__ WB1h, const short* __restrict__ WB1l,
                              const short* __restrict__ WB2h, const short* __restrict__ WB2l,
                              const float* __restrict__ bconv, const float* __restrict__ bih,
                              const float* __restrict__ bhh) {
    __shared__ short s_hh[32][72];
    __shared__ short s_hl[32][72];
    __shared__ short s_mh[32][72];
    __shared__ short s_ml[32][72];
    __shared__ float s_agg[32][68];
    int tid = threadIdx.x;
    int nbase = blockIdx.x * 32;
    int lane = tid & 63, w = tid >> 6;
    int l15 = lane & 15, lhi = lane >> 4;

    {
        int nt = tid >> 3, q = tid & 7;
        int n = nbase + nt;
#pragma unroll
        for (int c4 = 0; c4 < 2; ++c4) {
            int col = q * 8 + c4 * 4;
            float4 v = *(const float4*)&hbuf[(size_t)n * 64 + col];
            unsigned h01 = pk2(v.x, v.y), h23 = pk2(v.z, v.w);
            float f0 = __uint_as_float(h01 << 16);
            float f1 = __uint_as_float(h01 & 0xffff0000u);
            float f2 = __uint_as_float(h23 << 16);
            float f3 = __uint_as_float(h23 & 0xffff0000u);
            unsigned l01 = pk2(v.x - f0, v.y - f1), l23 = pk2(v.z - f2, v.w - f3);
            *(unsigned*)&s_hh[nt][col]     = h01;
            *(unsigned*)&s_hh[nt][col + 2] = h23;
            *(unsigned*)&s_hl[nt][col]     = l01;
            *(unsigned*)&s_hl[nt][col + 2] = l23;
        }
        float4 aggv[2];
#pragma unroll
        for (int c4 = 0; c4 < 2; ++c4)
            aggv[c4] = *(const float4*)&bconv[q * 8 + c4 * 4];
        int rs = rowptr[n], rend = rowptr[n + 1];
        for (int qq = rs; qq < rend; ++qq) {
            const float* mrow = msg + (size_t)perm[qq] * 64 + q * 8;
#pragma unroll
            for (int c4 = 0; c4 < 2; ++c4) {
                float4 mv = *(const float4*)&mrow[c4 * 4];
                aggv[c4].x += mv.x; aggv[c4].y += mv.y;
                aggv[c4].z += mv.z; aggv[c4].w += mv.w;
            }
        }
#pragma unroll
        for (int c4 = 0; c4 < 2; ++c4)
            *(float4*)&s_agg[nt][q * 8 + c4 * 4] = aggv[c4];
    }
    __syncthreads();

    union U { int4 i4; bf16x8 v; };
    U ah[2][2], al[2][2];
#pragma unroll
    for (int m = 0; m < 2; ++m)
#pragma unroll
        for (int c = 0; c < 2; ++c) {
            ah[m][c].i4 = *(const int4*)&s_hh[m * 16 + l15][c * 32 + lhi * 8];
            al[m][c].i4 = *(const int4*)&s_hl[m * 16 + l15][c * 32 + lhi * 8];
        }

    const int4* B1h = (const int4*)WB1h;
    const int4* B1l = (const int4*)WB1l;
    const int4* B2h = (const int4*)WB2h;
    const int4* B2l = (const int4*)WB2l;

    f32x4 C0[2], G[3][2], I[3][2];

    {
        int ot = w;
        U bh0, bh1, bl0, bl1;
        bh0.i4 = B1h[(ot * 2 + 0) * 64 + lane];
        bh1.i4 = B1h[(ot * 2 + 1) * 64 + lane];
        bl0.i4 = B1l[(ot * 2 + 0) * 64 + lane];
        bl1.i4 = B1l[(ot * 2 + 1) * 64 + lane];
#pragma unroll
        for (int m = 0; m < 2; ++m) {
            f32x4 c;
#pragma unroll
            for (int r = 0; r < 4; ++r) c[r] = s_agg[m * 16 + lhi * 4 + r][w * 16 + l15];
            c = __builtin_amdgcn_mfma_f32_16x16x32_bf16(ah[m][0].v, bh0.v, c, 0, 0, 0);
            c = __builtin_amdgcn_mfma_f32_16x16x32_bf16(ah[m][1].v, bh1.v, c, 0, 0, 0);
            c = __builtin_amdgcn_mfma_f32_16x16x32_bf16(al[m][0].v, bh0.v, c, 0, 0, 0);
            c = __builtin_amdgcn_mfma_f32_16x16x32_bf16(al[m][1].v, bh1.v, c, 0, 0, 0);
            c = __builtin_amdgcn_mfma_f32_16x16x32_bf16(ah[m][0].v, bl0.v, c, 0, 0, 0);
            c = __builtin_amdgcn_mfma_f32_16x16x32_bf16(ah[m][1].v, bl1.v, c, 0, 0, 0);
            C0[m] = c;
        }
    }
#pragma unroll
    for (int m = 0; m < 2; ++m)
#pragma unroll
        for (int r = 0; r < 4; ++r) {
            float mv = fmaxf(C0[m][r], 0.0f);
            int row = m * 16 + lhi * 4 + r, col = w * 16 + l15;
            unsigned hs = bf1(mv);
            float lof = mv - __uint_as_float(hs << 16);
            s_mh[row][col] = (short)hs;
            s_ml[row][col] = (short)bf1(lof);
        }
#pragma unroll
    for (int p = 1; p < 4; ++p) {
        int ot = p * 4 + w;
        U bh0, bh1, bl0, bl1;
        bh0.i4 = B1h[(ot * 2 + 0) * 64 + lane];
        bh1.i4 = B1h[(ot * 2 + 1) * 64 + lane];
        bl0.i4 = B1l[(ot * 2 + 0) * 64 + lane];
        bl1.i4 = B1l[(ot * 2 + 1) * 64 + lane];
        float bv = bhh[(p - 1) * 64 + w * 16 + l15];
#pragma unroll
        for (int m = 0; m < 2; ++m) {
            f32x4 c = {bv, bv, bv, bv};
            c = __builtin_amdgcn_mfma_f32_16x16x32_bf16(ah[m][0].v, bh0.v, c, 0, 0, 0);
            c = __builtin_amdgcn_mfma_f32_16x16x32_bf16(ah[m][1].v, bh1.v, c, 0, 0, 0);
            c = __builtin_amdgcn_mfma_f32_16x16x32_bf16(al[m][0].v, bh0.v, c, 0, 0, 0);
            c = __builtin_amdgcn_mfma_f32_16x16x32_bf16(al[m][1].v, bh1.v, c, 0, 0, 0);
            c = __builtin_amdgcn_mfma_f32_16x16x32_bf16(ah[m][0].v, bl0.v, c, 0, 0, 0);
            c = __builtin_amdgcn_mfma_f32_16x16x32_bf16(ah[m][1].v, bl1.v, c, 0, 0, 0);
            G[p - 1][m] = c;
        }
    }
    __syncthreads();
    U mh[2][2], ml[2][2];
#pragma unroll
    for (int m = 0; m < 2; ++m)
#pragma unroll
        for (int c = 0; c < 2; ++c) {
            mh[m][c].i4 = *(const int4*)&s_mh[m * 16 + l15][c * 32 + lhi * 8];
            ml[m][c].i4 = *(const int4*)&s_ml[m * 16 + l15][c * 32 + lhi * 8];
        }
#pragma unroll
    for (int p = 0; p < 3; ++p) {
        int ot = p * 4 + w;
        U bh0, bh1, bl0, bl1;
        bh0.i4 = B2h[(ot * 2 + 0) * 64 + lane];
        bh1.i4 = B2h[(ot * 2 + 1) * 64 + lane];
        bl0.i4 = B2l[(ot * 2 + 0) * 64 + lane];
        bl1.i4 = B2l[(ot * 2 + 1) * 64 + lane];
        float bv = bih[p * 64 + w * 16 + l15];
#pragma unroll
        for (int m = 0; m < 2; ++m) {
            f32x4 c = {bv, bv, bv, bv};
            c = __builtin_amdgcn_mfma_f32_16x16x32_bf16(mh[m][0].v, bh0.v, c, 0, 0, 0);
            c = __builtin_amdgcn_mfma_f32_16x16x32_bf16(mh[m][1].v, bh1.v, c, 0, 0, 0);
            c = __builtin_amdgcn_mfma_f32_16x16x32_bf16(ml[m][0].v, bh0.v, c, 0, 0, 0);
            c = __builtin_amdgcn_mfma_f32_16x16x32_bf16(ml[m][1].v, bh1.v, c, 0, 0, 0);
            c = __builtin_amdgcn_mfma_f32_16x16x32_bf16(mh[m][0].v, bl0.v, c, 0, 0, 0);
            c = __builtin_amdgcn_mfma_f32_16x16x32_bf16(mh[m][1].v, bl1.v, c, 0, 0, 0);
            I[p][m] = c;
        }
    }
#pragma unroll
    for (int m = 0; m < 2; ++m)
#pragma unroll
        for (int r = 0; r < 4; ++r) {
            int row = m * 16 + lhi * 4 + r;
            int n = nbase + row;
            int col = w * 16 + l15;
            float hold = __uint_as_float(((unsigned)(unsigned short)s_hh[row][col]) << 16)
                       + __uint_as_float(((unsigned)(unsigned short)s_hl[row][col]) << 16);
            float rg = sigmoidf_(I[0][m][r] + G[0][m][r]);
            float z  = sigmoidf_(I[1][m][r] + G[1][m][r]);
            float nn = tanhf_(I[2][m][r] + rg * G[2][m][r]);
            hbuf[(size_t)n * 64 + col] = (1.0f - z) * nn + z * hold;
        }
}

// Fused Set2Set (3 iterations) + readout MLP. 256 threads (4 waves) per graph.
__launch_bounds__(256)
__global__ void k_set2set(const float* __restrict__ hbuf, const int* __restrict__ offs,
                          const float* __restrict__ t, const float* __restrict__ p,
                          const float* __restrict__ lwihT, const float* __restrict__ lwhhT,
                          const float* __restrict__ l_bih, const float* __restrict__ l_bhh,
                          const float* __restrict__ W1, const float* __restrict__ b1,
                          const float* __restrict__ W2, const float* __restrict__ b2,
                          const float* __restrict__ W3, const float* __restrict__ b3,
                          float* __restrict__ y) {
    __shared__ float s_qs[192];       // [0..127]=q_star, [128..191]=qh
    __shared__ float s_g[256];
    __shared__ float s_racc[4][64];
    __shared__ float s_m[4], s_l[4];
    __shared__ float s_y[64];
    int b = blockIdx.x;
    int tid = threadIdx.x;
    int w = tid >> 6, lane = tid & 63;
    int s = offs[b], e = offs[b + 1];
    float bi = l_bih[tid] + l_bhh[tid];
    float qc = 0.f;                   // live in wave-0 lanes

    if (tid < 192) s_qs[tid] = 0.f;
    __syncthreads();

    for (int iter = 0; iter < 3; ++iter) {
        float g = bi;
#pragma unroll 8
        for (int i = 0; i < 128; ++i) g = fmaf(s_qs[i], lwihT[i * 256 + tid], g);
#pragma unroll 8
        for (int i = 0; i < 64; ++i)  g = fmaf(s_qs[128 + i], lwhhT[i * 256 + tid], g);
        s_g[tid] = g;
        __syncthreads();
        if (w == 0) {
            float ci = sigmoidf_(s_g[lane]);
            float cf = sigmoidf_(s_g[64 + lane]);
            float cg = tanhf_(s_g[128 + lane]);
            float co = sigmoidf_(s_g[192 + lane]);
            qc = cf * qc + ci * cg;
            float qh = co * tanhf_(qc);
            s_qs[lane] = qh;
            s_qs[128 + lane] = qh;
        }
        __syncthreads();
        float qv = s_qs[128 + lane];
        float mx = -1e30f, l = 0.0f, racc = 0.0f;
        for (int n = s + w; n < e; n += 4) {
            float xv = hbuf[(size_t)n * 64 + lane];
            float prod = xv * qv;
#pragma unroll
            for (int off = 32; off > 0; off >>= 1) prod += __shfl_xor(prod, off);
            float mnew = fmaxf(mx, prod);
            float scale = __expf(mx - mnew);
            float wgt = __expf(prod - mnew);
            l = l * scale + wgt;
            racc = racc * scale + wgt * xv;
            mx = mnew;
        }
        s_racc[w][lane] = racc;
        if (lane == 0) { s_m[w] = mx; s_l[w] = l; }
        __syncthreads();
        if (w == 0) {
            float M = fmaxf(fmaxf(s_m[0], s_m[1]), fmaxf(s_m[2], s_m[3]));
            float L = 0.f, R = 0.f;
#pragma unroll
            for (int ww = 0; ww < 4; ++ww) {
                float sc = __expf(s_m[ww] - M);
                L += s_l[ww] * sc;
                R = fmaf(s_racc[ww][lane], sc, R);
            }
            s_qs[64 + lane] = (e > s) ? (R / L) : 0.0f;
        }
        __syncthreads();
    }
    if (w == 0) {
        float acc = b1[lane];
#pragma unroll 8
        for (int i = 0; i < 128; ++i) acc = fmaf(s_qs[i], W1[i * 64 + lane], acc);
        acc = fmaf(t[b], W1[128 * 64 + lane], acc);
        acc = fmaf(p[b], W1[129 * 64 + lane], acc);
        acc = fmaxf(acc, 0.0f);
        s_y[lane] = acc;
        float acc2 = b2[lane];
#pragma unroll 8
        for (int i = 0; i < 64; ++i) acc2 = fmaf(s_y[i], W2[i * 64 + lane], acc2);
        acc2 = fmaxf(acc2, 0.0f);
        float part = acc2 * W3[lane];
#pragma unroll
        for (int off = 32; off > 0; off >>= 1) part += __shfl_xor(part, off);
        if (lane == 0) y[b] = part + b3[0];
    }
}

extern "C" void kernel_launch(void* const* d_in, const int* in_sizes, int n_in,
                              void* d_out, int out_size, void* d_ws, size_t ws_size,
                              hipStream_t stream) {
    const float* x     = (const float*)d_in[0];
    const int*   ei    = (const int*)  d_in[1];
    const float* ea    = (const float*)d_in[2];
    const int*   batch = (const int*)  d_in[3];
    const float* t     = (const float*)d_in[4];
    const float* p     = (const float*)d_in[5];
    const float* W0    = (const float*)d_in[7];
    const float* b0    = (const float*)d_in[8];
    const float* We1   = (const float*)d_in[9];
    const float* be1   = (const float*)d_in[10];
    const float* We2   = (const float*)d_in[11];
    const float* be2   = (const float*)d_in[12];
    const float* Wroot = (const float*)d_in[13];
    const float* bconv = (const float*)d_in[14];
    const float* gwih  = (const float*)d_in[15];
    const float* gwhh  = (const float*)d_in[16];
    const float* gbih  = (const float*)d_in[17];
    const float* gbhh  = (const float*)d_in[18];
    const float* lwih  = (const float*)d_in[19];
    const float* lwhh  = (const float*)d_in[20];
    const float* lbih  = (const float*)d_in[21];
    const float* lbhh  = (const float*)d_in[22];
    const float* W1    = (const float*)d_in[23];
    const float* b1    = (const float*)d_in[24];
    const float* W2    = (const float*)d_in[25];
    const float* b2    = (const float*)d_in[26];
    const float* W3    = (const float*)d_in[27];
    const float* b3    = (const float*)d_in[28];
    float* y = (float*)d_out;

    char* ws = (char*)d_ws;
    size_t off = 0;
    auto alloc = [&](size_t nbytes) {
        void* ptr = (void*)(ws + off);
        off += align_up(nbytes, 256);
        return ptr;
    };
    float* hbuf   = (float*)alloc((size_t)N_NODES * 64 * 4);
    float* reb    = (float*)alloc((size_t)N_EDGES * 64 * 4);
    float* msg    = (float*)alloc((size_t)N_EDGES * 64 * 4);
    short* We2b   = (short*)alloc((size_t)65 * 4096 * 2);
    short* WB1h   = (short*)alloc(16384 * 2);
    short* WB1l   = (short*)alloc(16384 * 2);
    short* WB2h   = (short*)alloc(12288 * 2);
    short* WB2l   = (short*)alloc(12288 * 2);
    float* lwihT  = (float*)alloc(32768 * 4);
    float* lwhhT  = (float*)alloc(16384 * 4);
    int*   offs   = (int*)  alloc((NB + 1) * 4);
    int*   deg    = (int*)  alloc(N_NODES * 4);
    int*   rowptr = (int*)  alloc((N_NODES + 1) * 4);
    int*   cursor = (int*)  alloc(N_NODES * 4);
    int*   perm   = (int*)  alloc(N_EDGES * 4);

    // ---- deg zero FIRST (stream-ordered before k_prep's count blocks) ----
    hipMemsetAsync(deg, 0, (size_t)N_NODES * 4, stream);
    // ---- mega-prep (prep + encoder + edge count) + CSR scan/fill ----
    k_prep<<<19045, 256, 0, stream>>>(We2, be2, We2b, Wroot, gwhh, gwih,
                                      WB1h, WB1l, WB2h, WB2l,
                                      lwih, lwhh, lwihT, lwhhT, batch, offs,
                                      x, W0, b0, hbuf, ea, We1, be1, reb,
                                      ei, deg);
    k_scan<<<1, 1024, 0, stream>>>(deg, rowptr, cursor);
    k_fill<<<(N_EDGES + 255) / 256, 256, 0, stream>>>(ei, cursor, perm);

    // ---- 4 message-passing + GRU iterations ----
    for (int it = 0; it < 4; ++it) {
        k_msg_mfma<<<256, 256, 0, stream>>>(hbuf, reb, We2b, ei, msg);
        k_node_update<<<N_NODES / 32, 256, 0, stream>>>(hbuf, msg, rowptr, perm,
                                                        WB1h, WB1l, WB2h, WB2l,
                                                        bconv, gbih, gbhh);
    }

    // ---- fused Set2Set (3 iters) + readout ----
    k_set2set<<<NB, 256, 0, stream>>>(hbuf, offs, t, p, lwihT, lwhhT, lbih, lbhh,
                                      W1, b1, W2, b2, W3, b3, y);
}

// Round 8
// 436.499 us; speedup vs baseline: 1.2611x; 1.2611x over previous
//
#include <hip/hip_runtime.h>
#include <math.h>

#define N_NODES 20000
#define N_EDGES 50000
#define NB      1024
#define IND     32
#define HDIM    64

typedef __attribute__((ext_vector_type(8))) short bf16x8;
typedef __attribute__((ext_vector_type(4))) float f32x4;

static inline size_t align_up(size_t x, size_t a) { return (x + a - 1) & ~(a - 1); }

__device__ __forceinline__ float sigmoidf_(float x) {
    return 1.0f / (1.0f + __expf(-x));
}
__device__ __forceinline__ float tanhf_(float x) {
    float xc = fminf(fmaxf(x, -15.0f), 15.0f);
    float e = __expf(2.0f * xc);
    return (e - 1.0f) / (e + 1.0f);
}
__device__ __forceinline__ unsigned pk2(float p0, float p1) {
    unsigned u0 = __float_as_uint(p0) + 0x8000u;
    unsigned u1 = __float_as_uint(p1) + 0x8000u;
    return __builtin_amdgcn_perm(u1, u0, 0x07060302u);
}
__device__ __forceinline__ unsigned bf1(float v) {
    return (__float_as_uint(v) + 0x8000u) >> 16;
}

// ---- mega-prep: We2b permute + wsplit + LSTM transposes + offsets + node_init +
//      edge_feat + edge degree count (deg pre-zeroed by memset BEFORE this kernel) ----
// grid = 1040 + 112 + 128 + 64 + 5 (=1349) + 5000 (node) + 12500 (edge) + 196 (count) = 19045
__global__ void k_prep(const float* __restrict__ We2, const float* __restrict__ be2,
                       short* __restrict__ We2b,
                       const float* __restrict__ Wroot, const float* __restrict__ gwhh,
                       const float* __restrict__ gwih,
                       short* __restrict__ WB1h, short* __restrict__ WB1l,
                       short* __restrict__ WB2h, short* __restrict__ WB2l,
                       const float* __restrict__ lwih, const float* __restrict__ lwhh,
                       float* __restrict__ lwihT, float* __restrict__ lwhhT,
                       const int* __restrict__ batch, int* __restrict__ offs,
                       const float* __restrict__ x, const float* __restrict__ W0,
                       const float* __restrict__ b0, float* __restrict__ hbuf,
                       const float* __restrict__ ea, const float* __restrict__ We1,
                       const float* __restrict__ be1, float* __restrict__ re,
                       const int* __restrict__ ei, int* __restrict__ deg) {
    int bid = blockIdx.x, tid = threadIdx.x;
    if (bid < 1040) {
        int idx = bid * 256 + tid;                 // 0 .. 65*4096-1
        int s = idx >> 12;
        int col = idx & 4095;
        int k = col >> 6, o = col & 63;
        float val = (s < 64) ? We2[k * 4096 + s * 64 + o] : be2[k * 64 + o];
        int dst = s * 4096 + (((o >> 4) * 128 + (k >> 5) * 64 + ((k >> 3) & 3) * 16 + (o & 15)) << 3) + (k & 7);
        We2b[dst] = (short)bf1(val);
    } else if (bid < 1152) {
        int idx = (bid - 1040) * 256 + tid;
        if (idx < 28672) {
            bool b1 = idx < 16384;
            int li = b1 ? idx : idx - 16384;
            int j = li & 7, lane = (li >> 3) & 63, c = (li >> 9) & 1, otile = li >> 10;
            int k = c * 32 + (lane >> 4) * 8 + j;
            int o = otile * 16 + (lane & 15);
            float val;
            if (b1) val = (o < 64) ? Wroot[k * 64 + o] : gwhh[(o - 64) * 64 + k];
            else    val = gwih[o * 64 + k];
            unsigned hs = bf1(val);
            float lo = val - __uint_as_float(hs << 16);
            unsigned ls = bf1(lo);
            if (b1) { WB1h[li] = (short)hs; WB1l[li] = (short)ls; }
            else    { WB2h[li] = (short)hs; WB2l[li] = (short)ls; }
        }
    } else if (bid < 1280) {
        int idx = (bid - 1152) * 256 + tid;        // < 32768 : lwihT[i*256+j] = lwih[j*128+i]
        int i = idx >> 8, j = idx & 255;
        lwihT[idx] = lwih[j * 128 + i];
    } else if (bid < 1344) {
        int idx = (bid - 1280) * 256 + tid;        // < 16384 : lwhhT[i*256+j] = lwhh[j*64+i]
        int i = idx >> 8, j = idx & 255;
        lwhhT[idx] = lwhh[j * 64 + i];
    } else if (bid < 1349) {
        int i = (bid - 1344) * 256 + tid;
        if (i <= NB) {
            int lo = 0, hi = N_NODES;
            while (lo < hi) { int mid = (lo + hi) >> 1; if (batch[mid] < i) lo = mid + 1; else hi = mid; }
            offs[i] = lo;
        }
    } else if (bid < 6349) {
        int w = tid >> 6, j = tid & 63;
        int n = (bid - 1349) * 4 + w;
        float acc = b0[j];
        const float* xr = x + n * IND;
#pragma unroll
        for (int i = 0; i < IND; ++i) acc = fmaf(xr[i], W0[i * 64 + j], acc);
        hbuf[n * 64 + j] = fmaxf(acc, 0.0f);
    } else if (bid < 18849) {
        int w = tid >> 6, j = tid & 63;
        int e = (bid - 6349) * 4 + w;
        if (e < N_EDGES) {
            float acc = be1[j];
            const float* er = ea + e * 6;
#pragma unroll
            for (int i = 0; i < 6; ++i) acc = fmaf(er[i], We1[i * 64 + j], acc);
            re[e * 64 + j] = fmaxf(acc, 0.0f);
        }
    } else {
        int e = (bid - 18849) * 256 + tid;
        if (e < N_EDGES) atomicAdd(&deg[ei[N_EDGES + e]], 1);
    }
}

__global__ void k_scan(const int* __restrict__ deg, int* __restrict__ rowptr, int* __restrict__ cursor) {
    __shared__ int s_w[16];
    int t = threadIdx.x;
    int base = t * 20;
    int v[20]; int s = 0;
#pragma unroll
    for (int i = 0; i < 20; ++i) {
        int idx = base + i;
        v[i] = (idx < N_NODES) ? deg[idx] : 0;
        s += v[i];
    }
    int lane = t & 63, w = t >> 6;
    int inc = s;
#pragma unroll
    for (int off = 1; off < 64; off <<= 1) {
        int o = __shfl_up(inc, off);
        if (lane >= off) inc += o;
    }
    if (lane == 63) s_w[w] = inc;
    __syncthreads();
    if (w == 0 && lane < 16) {
        int x = s_w[lane];
        int xs = x;
#pragma unroll
        for (int off = 1; off < 16; off <<= 1) {
            int o = __shfl_up(xs, off);
            if (lane >= off) xs += o;
        }
        s_w[lane] = xs - x;
    }
    __syncthreads();
    int run = s_w[w] + (inc - s);
#pragma unroll
    for (int i = 0; i < 20; ++i) {
        int idx = base + i;
        if (idx < N_NODES) { rowptr[idx] = run; cursor[idx] = run; }
        else if (idx == N_NODES) rowptr[idx] = run;
        run += v[i];
    }
}

__global__ void k_fill(const int* __restrict__ ei, int* __restrict__ cursor, int* __restrict__ perm) {
    int e = blockIdx.x * 256 + threadIdx.x;
    if (e < N_EDGES) {
        int pos = atomicAdd(&cursor[ei[N_EDGES + e]], 1);
        perm[pos] = e;
    }
}

// One step's compute, TRANSPOSED orientation: C'[o][e] = W^T * re^T, so the per-slab
// v-scale is a per-lane scalar (col = lane&15 = edge). 8 MFMA + 16 fmaf.
#define MSG_STEP_COMPUTE(BB0, BB1, PP)                                                              \
    _Pragma("unroll")                                                                               \
    for (int m = 0; m < 4; ++m) {                                                                   \
        f32x4 tt = __builtin_amdgcn_mfma_f32_16x16x32_bf16(BB0.v, a_re[m][0].v, zero4, 0, 0, 0);    \
        tt = __builtin_amdgcn_mfma_f32_16x16x32_bf16(BB1.v, a_re[m][1].v, tt, 0, 0, 0);             \
        macc[m][0] = fmaf(vsc[PP][m], tt[0], macc[m][0]);                                           \
        macc[m][1] = fmaf(vsc[PP][m], tt[1], macc[m][1]);                                           \
        macc[m][2] = fmaf(vsc[PP][m], tt[2], macc[m][2]);                                           \
        macc[m][3] = fmaf(vsc[PP][m], tt[3], macc[m][3]);                                           \
    }

// msg kernel — R2-EXACT revert (measured 46.6 us): transposed MFMA, register-rotated W
// prefetch, no in-loop barriers, 64 edges/block, 4 waves, full TLP. R4-R7 established
// this sits on the per-CU L2-delivery cap (~15.5 B/cyc x 1.6 MB/CU W-stream) and every
// traffic-reducing restructure lost more to serialization than it gained in bytes.
__launch_bounds__(256, 4)
__global__ void k_msg_mfma(const float* __restrict__ hbuf, const float* __restrict__ reb,
                           const short* __restrict__ We2b, const int* __restrict__ ei,
                           float* __restrict__ msg) {
    __shared__ union {
        float v[64][64];     // [h][e] during the loop + bias
        float out[64][68];   // [e][o] for the coalescing store (padded: 68)
    } s_u;
    int tid = threadIdx.x;
    int eb = blockIdx.x * 64;
    int lane = tid & 63;
    int w = tid >> 6;
    int l15 = lane & 15, lhi = lane >> 4;

    // stage s_v transposed
    {
        int se = tid >> 2;
        int sh = tid & 3;
        int ge = eb + se;
        const float* rowp = (ge < N_EDGES) ? (hbuf + (size_t)ei[ge] * 64) : (const float*)0;
#pragma unroll
        for (int rr4 = 0; rr4 < 4; ++rr4) {
            int hb = rr4 * 16 + sh * 4;
            float4 vv = rowp ? *(const float4*)(rowp + hb) : make_float4(0.f, 0.f, 0.f, 0.f);
            s_u.v[hb + 0][se] = vv.x; s_u.v[hb + 1][se] = vv.y;
            s_u.v[hb + 2][se] = vv.z; s_u.v[hb + 3][se] = vv.w;
        }
    }

    // pack re fragments once (used as the B operand: B[k][col=e])
    union U { int4 i4; bf16x8 v; };
    U a_re[4][2];
#pragma unroll
    for (int m = 0; m < 4; ++m) {
        int ge = eb + m * 16 + l15;
        if (ge < N_EDGES) {
            const float* rp = reb + (size_t)ge * 64 + lhi * 8;
            float4 x0 = *(const float4*)(rp);
            float4 x1 = *(const float4*)(rp + 4);
            float4 y0 = *(const float4*)(rp + 32);
            float4 y1 = *(const float4*)(rp + 36);
            a_re[m][0].i4 = make_int4(pk2(x0.x, x0.y), pk2(x0.z, x0.w), pk2(x1.x, x1.y), pk2(x1.z, x1.w));
            a_re[m][1].i4 = make_int4(pk2(y0.x, y0.y), pk2(y0.z, y0.w), pk2(y1.x, y1.y), pk2(y1.z, y1.w));
        } else {
            a_re[m][0].i4 = make_int4(0, 0, 0, 0);
            a_re[m][1].i4 = make_int4(0, 0, 0, 0);
        }
    }

    // W prefetch (A operand): 4 rotating register sets, depth 4
    const int4* bp0 = (const int4*)We2b + (w * 128 + lane);   // slab stride = 512 int4
    const int4* bp1 = bp0 + 64;
    int4 Sc0[4], Sc1[4];
#pragma unroll
    for (int j = 0; j < 4; ++j) {
        Sc0[j] = bp0[j * 512];
        Sc1[j] = bp1[j * 512];
    }

    __syncthreads();

    const f32x4 zero4 = {0.f, 0.f, 0.f, 0.f};
    f32x4 macc[4];
#pragma unroll
    for (int m = 0; m < 4; ++m) macc[m] = zero4;

    // per-lane v scalars, parity double-buffered (1 step ahead)
    float vsc[2][4];
#pragma unroll
    for (int m = 0; m < 4; ++m) vsc[0][m] = s_u.v[0][m * 16 + l15];

    for (int g = 0; g < 16; ++g) {
#pragma unroll
        for (int j = 0; j < 4; ++j) {
            const int p = j & 1, q = p ^ 1;
            int s = g * 4 + j;
            int snext = (s < 63) ? (s + 1) : 63;
#pragma unroll
            for (int m = 0; m < 4; ++m) vsc[q][m] = s_u.v[snext][m * 16 + l15];
            U bb0, bb1; bb0.i4 = Sc0[j]; bb1.i4 = Sc1[j];
            MSG_STEP_COMPUTE(bb0, bb1, p)
            int sload = (s + 4 <= 64) ? (s + 4) : 64;
            Sc0[j] = bp0[sload * 512];
            Sc1[j] = bp1[sload * 512];
        }
    }

    // bias slab (set 0 holds slab 64): msg^T += be2^T @ v^T
    {
        U bb0, bb1; bb0.i4 = Sc0[0]; bb1.i4 = Sc1[0];
#pragma unroll
        for (int m = 0; m < 4; ++m) {
            int e = m * 16 + l15;
            U a0, a1;
            a0.i4 = make_int4(
                pk2(s_u.v[lhi * 8 + 0][e], s_u.v[lhi * 8 + 1][e]),
                pk2(s_u.v[lhi * 8 + 2][e], s_u.v[lhi * 8 + 3][e]),
                pk2(s_u.v[lhi * 8 + 4][e], s_u.v[lhi * 8 + 5][e]),
                pk2(s_u.v[lhi * 8 + 6][e], s_u.v[lhi * 8 + 7][e]));
            a1.i4 = make_int4(
                pk2(s_u.v[32 + lhi * 8 + 0][e], s_u.v[32 + lhi * 8 + 1][e]),
                pk2(s_u.v[32 + lhi * 8 + 2][e], s_u.v[32 + lhi * 8 + 3][e]),
                pk2(s_u.v[32 + lhi * 8 + 4][e], s_u.v[32 + lhi * 8 + 5][e]),
                pk2(s_u.v[32 + lhi * 8 + 6][e], s_u.v[32 + lhi * 8 + 7][e]));
            macc[m] = __builtin_amdgcn_mfma_f32_16x16x32_bf16(bb0.v, a0.v, macc[m], 0, 0, 0);
            macc[m] = __builtin_amdgcn_mfma_f32_16x16x32_bf16(bb1.v, a1.v, macc[m], 0, 0, 0);
        }
    }

    // transpose through LDS: macc holds C'[o][e]; emit msg[e][o] coalesced
    __syncthreads();   // all waves done reading s_u.v
#pragma unroll
    for (int m = 0; m < 4; ++m) {
        // lane (lhi,l15) holds rows o = w*16+lhi*4+0..3, col e = m*16+l15
        *(float4*)&s_u.out[m * 16 + l15][w * 16 + lhi * 4] =
            make_float4(macc[m][0], macc[m][1], macc[m][2], macc[m][3]);
    }
    __syncthreads();
    {
        int er = tid >> 2, qc = tid & 3;
        int ge = eb + er;
        if (ge < N_EDGES) {
#pragma unroll
            for (int i = 0; i < 4; ++i)
                *(float4*)&msg[(size_t)ge * 64 + qc * 16 + i * 4] =
                    *(const float4*)&s_u.out[er][qc * 16 + i * 4];
        }
    }
}

// MFMA node update: conv + GRU with split-bf16 weights. 32 nodes / block (625 blocks).
__launch_bounds__(256, 4)
__global__ void k_node_update(float* __restrict__ hbuf, const float* __restrict__ msg,
                              const int* __restrict__ rowptr, const int* __restrict__ perm,
                              const short* __restrict__ WB1h, const short* __restrict__ WB1l,
                              const short* __restrict__ WB2h, const short* __restrict__ WB2l,
                              const float* __restrict__ bconv, const float* __restrict__ bih,
                              const float* __restrict__ bhh) {
    __shared__ short s_hh[32][72];
    __shared__ short s_hl[32][72];
    __shared__ short s_mh[32][72];
    __shared__ short s_ml[32][72];
    __shared__ float s_agg[32][68];
    int tid = threadIdx.x;
    int nbase = blockIdx.x * 32;
    int lane = tid & 63, w = tid >> 6;
    int l15 = lane & 15, lhi = lane >> 4;

    {
        int nt = tid >> 3, q = tid & 7;
        int n = nbase + nt;
#pragma unroll
        for (int c4 = 0; c4 < 2; ++c4) {
            int col = q * 8 + c4 * 4;
            float4 v = *(const float4*)&hbuf[(size_t)n * 64 + col];
            unsigned h01 = pk2(v.x, v.y), h23 = pk2(v.z, v.w);
            float f0 = __uint_as_float(h01 << 16);
            float f1 = __uint_as_float(h01 & 0xffff0000u);
            float f2 = __uint_as_float(h23 << 16);
            float f3 = __uint_as_float(h23 & 0xffff0000u);
            unsigned l01 = pk2(v.x - f0, v.y - f1), l23 = pk2(v.z - f2, v.w - f3);
            *(unsigned*)&s_hh[nt][col]     = h01;
            *(unsigned*)&s_hh[nt][col + 2] = h23;
            *(unsigned*)&s_hl[nt][col]     = l01;
            *(unsigned*)&s_hl[nt][col + 2] = l23;
        }
        float4 aggv[2];
#pragma unroll
        for (int c4 = 0; c4 < 2; ++c4)
            aggv[c4] = *(const float4*)&bconv[q * 8 + c4 * 4];
        int rs = rowptr[n], rend = rowptr[n + 1];
        for (int qq = rs; qq < rend; ++qq) {
            const float* mrow = msg + (size_t)perm[qq] * 64 + q * 8;
#pragma unroll
            for (int c4 = 0; c4 < 2; ++c4) {
                float4 mv = *(const float4*)&mrow[c4 * 4];
                aggv[c4].x += mv.x; aggv[c4].y += mv.y;
                aggv[c4].z += mv.z; aggv[c4].w += mv.w;
            }
        }
#pragma unroll
        for (int c4 = 0; c4 < 2; ++c4)
            *(float4*)&s_agg[nt][q * 8 + c4 * 4] = aggv[c4];
    }
    __syncthreads();

    union U { int4 i4; bf16x8 v; };
    U ah[2][2], al[2][2];
#pragma unroll
    for (int m = 0; m < 2; ++m)
#pragma unroll
        for (int c = 0; c < 2; ++c) {
            ah[m][c].i4 = *(const int4*)&s_hh[m * 16 + l15][c * 32 + lhi * 8];
            al[m][c].i4 = *(const int4*)&s_hl[m * 16 + l15][c * 32 + lhi * 8];
        }

    const int4* B1h = (const int4*)WB1h;
    const int4* B1l = (const int4*)WB1l;
    const int4* B2h = (const int4*)WB2h;
    const int4* B2l = (const int4*)WB2l;

    f32x4 C0[2], G[3][2], I[3][2];

    {
        int ot = w;
        U bh0, bh1, bl0, bl1;
        bh0.i4 = B1h[(ot * 2 + 0) * 64 + lane];
        bh1.i4 = B1h[(ot * 2 + 1) * 64 + lane];
        bl0.i4 = B1l[(ot * 2 + 0) * 64 + lane];
        bl1.i4 = B1l[(ot * 2 + 1) * 64 + lane];
#pragma unroll
        for (int m = 0; m < 2; ++m) {
            f32x4 c;
#pragma unroll
            for (int r = 0; r < 4; ++r) c[r] = s_agg[m * 16 + lhi * 4 + r][w * 16 + l15];
            c = __builtin_amdgcn_mfma_f32_16x16x32_bf16(ah[m][0].v, bh0.v, c, 0, 0, 0);
            c = __builtin_amdgcn_mfma_f32_16x16x32_bf16(ah[m][1].v, bh1.v, c, 0, 0, 0);
            c = __builtin_amdgcn_mfma_f32_16x16x32_bf16(al[m][0].v, bh0.v, c, 0, 0, 0);
            c = __builtin_amdgcn_mfma_f32_16x16x32_bf16(al[m][1].v, bh1.v, c, 0, 0, 0);
            c = __builtin_amdgcn_mfma_f32_16x16x32_bf16(ah[m][0].v, bl0.v, c, 0, 0, 0);
            c = __builtin_amdgcn_mfma_f32_16x16x32_bf16(ah[m][1].v, bl1.v, c, 0, 0, 0);
            C0[m] = c;
        }
    }
#pragma unroll
    for (int m = 0; m < 2; ++m)
#pragma unroll
        for (int r = 0; r < 4; ++r) {
            float mv = fmaxf(C0[m][r], 0.0f);
            int row = m * 16 + lhi * 4 + r, col = w * 16 + l15;
            unsigned hs = bf1(mv);
            float lof = mv - __uint_as_float(hs << 16);
            s_mh[row][col] = (short)hs;
            s_ml[row][col] = (short)bf1(lof);
        }
#pragma unroll
    for (int p = 1; p < 4; ++p) {
        int ot = p * 4 + w;
        U bh0, bh1, bl0, bl1;
        bh0.i4 = B1h[(ot * 2 + 0) * 64 + lane];
        bh1.i4 = B1h[(ot * 2 + 1) * 64 + lane];
        bl0.i4 = B1l[(ot * 2 + 0) * 64 + lane];
        bl1.i4 = B1l[(ot * 2 + 1) * 64 + lane];
        float bv = bhh[(p - 1) * 64 + w * 16 + l15];
#pragma unroll
        for (int m = 0; m < 2; ++m) {
            f32x4 c = {bv, bv, bv, bv};
            c = __builtin_amdgcn_mfma_f32_16x16x32_bf16(ah[m][0].v, bh0.v, c, 0, 0, 0);
            c = __builtin_amdgcn_mfma_f32_16x16x32_bf16(ah[m][1].v, bh1.v, c, 0, 0, 0);
            c = __builtin_amdgcn_mfma_f32_16x16x32_bf16(al[m][0].v, bh0.v, c, 0, 0, 0);
            c = __builtin_amdgcn_mfma_f32_16x16x32_bf16(al[m][1].v, bh1.v, c, 0, 0, 0);
            c = __builtin_amdgcn_mfma_f32_16x16x32_bf16(ah[m][0].v, bl0.v, c, 0, 0, 0);
            c = __builtin_amdgcn_mfma_f32_16x16x32_bf16(ah[m][1].v, bl1.v, c, 0, 0, 0);
            G[p - 1][m] = c;
        }
    }
    __syncthreads();
    U mh[2][2], ml[2][2];
#pragma unroll
    for (int m = 0; m < 2; ++m)
#pragma unroll
        for (int c = 0; c < 2; ++c) {
            mh[m][c].i4 = *(const int4*)&s_mh[m * 16 + l15][c * 32 + lhi * 8];
            ml[m][c].i4 = *(const int4*)&s_ml[m * 16 + l15][c * 32 + lhi * 8];
        }
#pragma unroll
    for (int p = 0; p < 3; ++p) {
        int ot = p * 4 + w;
        U bh0, bh1, bl0, bl1;
        bh0.i4 = B2h[(ot * 2 + 0) * 64 + lane];
        bh1.i4 = B2h[(ot * 2 + 1) * 64 + lane];
        bl0.i4 = B2l[(ot * 2 + 0) * 64 + lane];
        bl1.i4 = B2l[(ot * 2 + 1) * 64 + lane];
        float bv = bih[p * 64 + w * 16 + l15];
#pragma unroll
        for (int m = 0; m < 2; ++m) {
            f32x4 c = {bv, bv, bv, bv};
            c = __builtin_amdgcn_mfma_f32_16x16x32_bf16(mh[m][0].v, bh0.v, c, 0, 0, 0);
            c = __builtin_amdgcn_mfma_f32_16x16x32_bf16(mh[m][1].v, bh1.v, c, 0, 0, 0);
            c = __builtin_amdgcn_mfma_f32_16x16x32_bf16(ml[m][0].v, bh0.v, c, 0, 0, 0);
            c = __builtin_amdgcn_mfma_f32_16x16x32_bf16(ml[m][1].v, bh1.v, c, 0, 0, 0);
            c = __builtin_amdgcn_mfma_f32_16x16x32_bf16(mh[m][0].v, bl0.v, c, 0, 0, 0);
            c = __builtin_amdgcn_mfma_f32_16x16x32_bf16(mh[m][1].v, bl1.v, c, 0, 0, 0);
            I[p][m] = c;
        }
    }
#pragma unroll
    for (int m = 0; m < 2; ++m)
#pragma unroll
        for (int r = 0; r < 4; ++r) {
            int row = m * 16 + lhi * 4 + r;
            int n = nbase + row;
            int col = w * 16 + l15;
            float hold = __uint_as_float(((unsigned)(unsigned short)s_hh[row][col]) << 16)
                       + __uint_as_float(((unsigned)(unsigned short)s_hl[row][col]) << 16);
            float rg = sigmoidf_(I[0][m][r] + G[0][m][r]);
            float z  = sigmoidf_(I[1][m][r] + G[1][m][r]);
            float nn = tanhf_(I[2][m][r] + rg * G[2][m][r]);
            hbuf[(size_t)n * 64 + col] = (1.0f - z) * nn + z * hold;
        }
}

// Fused Set2Set (3 iterations) + readout MLP — 4 graphs per block (grid 256):
//   The LSTM matvec re-read lwihT/lwhhT (196 KB) per graph per iter (~600 MB L2->CU
//   total, the same per-CU delivery currency k_msg is bound by). Now each weight
//   element is loaded once and fmaf'd into 4 graphs' accumulators (traffic /4).
//   Wave w owns graph blockIdx.x*4+w: LSTM cell, online-softmax pooling (full-64-lane
//   shfl dot, single-wave so no cross-wave combine), and readout. All fp32, same math.
__launch_bounds__(256)
__global__ void k_set2set(const float* __restrict__ hbuf, const int* __restrict__ offs,
                          const float* __restrict__ t, const float* __restrict__ p,
                          const float* __restrict__ lwihT, const float* __restrict__ lwhhT,
                          const float* __restrict__ l_bih, const float* __restrict__ l_bhh,
                          const float* __restrict__ W1, const float* __restrict__ b1,
                          const float* __restrict__ W2, const float* __restrict__ b2,
                          const float* __restrict__ W3, const float* __restrict__ b3,
                          float* __restrict__ y) {
    __shared__ float s_qs[4][192];    // per graph: [0..63]=q, [64..127]=r, [128..191]=qh
    __shared__ float s_g[4][256];
    __shared__ float s_y[4][64];
    int tid = threadIdx.x;
    int w = tid >> 6, lane = tid & 63;
    int gb = blockIdx.x * 4;
    int s = offs[gb + w], e = offs[gb + w + 1];
    float bi = l_bih[tid] + l_bhh[tid];
    float qc = 0.f;                   // graph-w LSTM cell state (lanes of wave w)

    if (tid < 192) {
        s_qs[0][tid] = 0.f; s_qs[1][tid] = 0.f;
        s_qs[2][tid] = 0.f; s_qs[3][tid] = 0.f;
    }
    __syncthreads();

    for (int iter = 0; iter < 3; ++iter) {
        // shared-weight matvec: one load feeds all 4 graphs
        float g0 = bi, g1 = bi, g2 = bi, g3 = bi;
#pragma unroll 8
        for (int i = 0; i < 128; ++i) {
            float wv = lwihT[i * 256 + tid];
            g0 = fmaf(s_qs[0][i], wv, g0);
            g1 = fmaf(s_qs[1][i], wv, g1);
            g2 = fmaf(s_qs[2][i], wv, g2);
            g3 = fmaf(s_qs[3][i], wv, g3);
        }
#pragma unroll 8
        for (int i = 0; i < 64; ++i) {
            float wv = lwhhT[i * 256 + tid];
            g0 = fmaf(s_qs[0][128 + i], wv, g0);
            g1 = fmaf(s_qs[1][128 + i], wv, g1);
            g2 = fmaf(s_qs[2][128 + i], wv, g2);
            g3 = fmaf(s_qs[3][128 + i], wv, g3);
        }
        s_g[0][tid] = g0; s_g[1][tid] = g1; s_g[2][tid] = g2; s_g[3][tid] = g3;
        __syncthreads();

        // LSTM cell: wave w, graph gb+w
        {
            float ci = sigmoidf_(s_g[w][lane]);
            float cf = sigmoidf_(s_g[w][64 + lane]);
            float cg = tanhf_(s_g[w][128 + lane]);
            float co = sigmoidf_(s_g[w][192 + lane]);
            qc = cf * qc + ci * cg;
            float qh = co * tanhf_(qc);
            s_qs[w][lane] = qh;
            s_qs[w][128 + lane] = qh;
        }
        // attention pooling: same wave reads its own writes (in-wave LDS ordering)
        float qv = s_qs[w][128 + lane];
        float mx = -1e30f, l = 0.0f, racc = 0.0f;
        for (int n = s; n < e; ++n) {
            float xv = hbuf[(size_t)n * 64 + lane];
            float prod = xv * qv;
#pragma unroll
            for (int off = 32; off > 0; off >>= 1) prod += __shfl_xor(prod, off);
            float mnew = fmaxf(mx, prod);
            float scale = __expf(mx - mnew);
            float wgt = __expf(prod - mnew);
            l = l * scale + wgt;
            racc = racc * scale + wgt * xv;
            mx = mnew;
        }
        s_qs[w][64 + lane] = (e > s) ? (racc / l) : 0.0f;
        __syncthreads();   // all graphs' q_star ready for next matvec
    }

    // readout: wave w computes graph gb+w
    {
        float acc = b1[lane];
#pragma unroll 8
        for (int i = 0; i < 128; ++i) acc = fmaf(s_qs[w][i], W1[i * 64 + lane], acc);
        acc = fmaf(t[gb + w], W1[128 * 64 + lane], acc);
        acc = fmaf(p[gb + w], W1[129 * 64 + lane], acc);
        acc = fmaxf(acc, 0.0f);
        s_y[w][lane] = acc;
        float acc2 = b2[lane];
#pragma unroll 8
        for (int i = 0; i < 64; ++i) acc2 = fmaf(s_y[w][i], W2[i * 64 + lane], acc2);
        acc2 = fmaxf(acc2, 0.0f);
        float part = acc2 * W3[lane];
#pragma unroll
        for (int off = 32; off > 0; off >>= 1) part += __shfl_xor(part, off);
        if (lane == 0) y[gb + w] = part + b3[0];
    }
}

extern "C" void kernel_launch(void* const* d_in, const int* in_sizes, int n_in,
                              void* d_out, int out_size, void* d_ws, size_t ws_size,
                              hipStream_t stream) {
    const float* x     = (const float*)d_in[0];
    const int*   ei    = (const int*)  d_in[1];
    const float* ea    = (const float*)d_in[2];
    const int*   batch = (const int*)  d_in[3];
    const float* t     = (const float*)d_in[4];
    const float* p     = (const float*)d_in[5];
    const float* W0    = (const float*)d_in[7];
    const float* b0    = (const float*)d_in[8];
    const float* We1   = (const float*)d_in[9];
    const float* be1   = (const float*)d_in[10];
    const float* We2   = (const float*)d_in[11];
    const float* be2   = (const float*)d_in[12];
    const float* Wroot = (const float*)d_in[13];
    const float* bconv = (const float*)d_in[14];
    const float* gwih  = (const float*)d_in[15];
    const float* gwhh  = (const float*)d_in[16];
    const float* gbih  = (const float*)d_in[17];
    const float* gbhh  = (const float*)d_in[18];
    const float* lwih  = (const float*)d_in[19];
    const float* lwhh  = (const float*)d_in[20];
    const float* lbih  = (const float*)d_in[21];
    const float* lbhh  = (const float*)d_in[22];
    const float* W1    = (const float*)d_in[23];
    const float* b1    = (const float*)d_in[24];
    const float* W2    = (const float*)d_in[25];
    const float* b2    = (const float*)d_in[26];
    const float* W3    = (const float*)d_in[27];
    const float* b3    = (const float*)d_in[28];
    float* y = (float*)d_out;

    char* ws = (char*)d_ws;
    size_t off = 0;
    auto alloc = [&](size_t nbytes) {
        void* ptr = (void*)(ws + off);
        off += align_up(nbytes, 256);
        return ptr;
    };
    float* hbuf   = (float*)alloc((size_t)N_NODES * 64 * 4);
    float* reb    = (float*)alloc((size_t)N_EDGES * 64 * 4);
    float* msg    = (float*)alloc((size_t)N_EDGES * 64 * 4);
    short* We2b   = (short*)alloc((size_t)65 * 4096 * 2);
    short* WB1h   = (short*)alloc(16384 * 2);
    short* WB1l   = (short*)alloc(16384 * 2);
    short* WB2h   = (short*)alloc(12288 * 2);
    short* WB2l   = (short*)alloc(12288 * 2);
    float* lwihT  = (float*)alloc(32768 * 4);
    float* lwhhT  = (float*)alloc(16384 * 4);
    int*   offs   = (int*)  alloc((NB + 1) * 4);
    int*   deg    = (int*)  alloc(N_NODES * 4);
    int*   rowptr = (int*)  alloc((N_NODES + 1) * 4);
    int*   cursor = (int*)  alloc(N_NODES * 4);
    int*   perm   = (int*)  alloc(N_EDGES * 4);

    // ---- deg zero FIRST (stream-ordered before k_prep's count blocks) ----
    hipMemsetAsync(deg, 0, (size_t)N_NODES * 4, stream);
    // ---- mega-prep (prep + encoder + edge count) + CSR scan/fill ----
    k_prep<<<19045, 256, 0, stream>>>(We2, be2, We2b, Wroot, gwhh, gwih,
                                      WB1h, WB1l, WB2h, WB2l,
                                      lwih, lwhh, lwihT, lwhhT, batch, offs,
                                      x, W0, b0, hbuf, ea, We1, be1, reb,
                                      ei, deg);
    k_scan<<<1, 1024, 0, stream>>>(deg, rowptr, cursor);
    k_fill<<<(N_EDGES + 255) / 256, 256, 0, stream>>>(ei, cursor, perm);

    // ---- 4 message-passing + GRU iterations ----
    for (int it = 0; it < 4; ++it) {
        k_msg_mfma<<<(N_EDGES + 63) / 64, 256, 0, stream>>>(hbuf, reb, We2b, ei, msg);
        k_node_update<<<N_NODES / 32, 256, 0, stream>>>(hbuf, msg, rowptr, perm,
                                                        WB1h, WB1l, WB2h, WB2l,
                                                        bconv, gbih, gbhh);
    }

    // ---- fused Set2Set (3 iters) + readout ----
    k_set2set<<<NB / 4, 256, 0, stream>>>(hbuf, offs, t, p, lwihT, lwhhT, lbih, lbhh,
                                          W1, b1, W2, b2, W3, b3, y);
}

// Round 10
// 409.778 us; speedup vs baseline: 1.3433x; 1.0652x over previous
//
#include <hip/hip_runtime.h>
#include <math.h>

#define N_NODES 20000
#define N_EDGES 50000
#define NB      1024
#define IND     32
#define HDIM    64

typedef __attribute__((ext_vector_type(8))) short bf16x8;
typedef __attribute__((ext_vector_type(4))) float f32x4;

static inline size_t align_up(size_t x, size_t a) { return (x + a - 1) & ~(a - 1); }

__device__ __forceinline__ float sigmoidf_(float x) {
    return 1.0f / (1.0f + __expf(-x));
}
__device__ __forceinline__ float tanhf_(float x) {
    float xc = fminf(fmaxf(x, -15.0f), 15.0f);
    float e = __expf(2.0f * xc);
    return (e - 1.0f) / (e + 1.0f);
}
__device__ __forceinline__ unsigned pk2(float p0, float p1) {
    unsigned u0 = __float_as_uint(p0) + 0x8000u;
    unsigned u1 = __float_as_uint(p1) + 0x8000u;
    return __builtin_amdgcn_perm(u1, u0, 0x07060302u);
}
__device__ __forceinline__ unsigned bf1(float v) {
    return (__float_as_uint(v) + 0x8000u) >> 16;
}

// ---- mega-prep: We2b permute + wsplit + LSTM transposes (PACKED-4 layout) + offsets +
//      node_init + edge_feat + edge degree count (deg pre-zeroed by memset) ----
// grid = 1040 + 112 + 128 + 64 + 5 (=1349) + 5000 (node) + 12500 (edge) + 196 (count) = 19045
__global__ void k_prep(const float* __restrict__ We2, const float* __restrict__ be2,
                       short* __restrict__ We2b,
                       const float* __restrict__ Wroot, const float* __restrict__ gwhh,
                       const float* __restrict__ gwih,
                       short* __restrict__ WB1h, short* __restrict__ WB1l,
                       short* __restrict__ WB2h, short* __restrict__ WB2l,
                       const float* __restrict__ lwih, const float* __restrict__ lwhh,
                       float* __restrict__ lwihT, float* __restrict__ lwhhT,
                       const int* __restrict__ batch, int* __restrict__ offs,
                       const float* __restrict__ x, const float* __restrict__ W0,
                       const float* __restrict__ b0, float* __restrict__ hbuf,
                       const float* __restrict__ ea, const float* __restrict__ We1,
                       const float* __restrict__ be1, float* __restrict__ re,
                       const int* __restrict__ ei, int* __restrict__ deg) {
    int bid = blockIdx.x, tid = threadIdx.x;
    if (bid < 1040) {
        int idx = bid * 256 + tid;                 // 0 .. 65*4096-1
        int s = idx >> 12;
        int col = idx & 4095;
        int k = col >> 6, o = col & 63;
        float val = (s < 64) ? We2[k * 4096 + s * 64 + o] : be2[k * 64 + o];
        int dst = s * 4096 + (((o >> 4) * 128 + (k >> 5) * 64 + ((k >> 3) & 3) * 16 + (o & 15)) << 3) + (k & 7);
        We2b[dst] = (short)bf1(val);
    } else if (bid < 1152) {
        int idx = (bid - 1040) * 256 + tid;
        if (idx < 28672) {
            bool b1 = idx < 16384;
            int li = b1 ? idx : idx - 16384;
            int j = li & 7, lane = (li >> 3) & 63, c = (li >> 9) & 1, otile = li >> 10;
            int k = c * 32 + (lane >> 4) * 8 + j;
            int o = otile * 16 + (lane & 15);
            float val;
            if (b1) val = (o < 64) ? Wroot[k * 64 + o] : gwhh[(o - 64) * 64 + k];
            else    val = gwih[o * 64 + k];
            unsigned hs = bf1(val);
            float lo = val - __uint_as_float(hs << 16);
            unsigned ls = bf1(lo);
            if (b1) { WB1h[li] = (short)hs; WB1l[li] = (short)ls; }
            else    { WB2h[li] = (short)hs; WB2l[li] = (short)ls; }
        }
    } else if (bid < 1280) {
        int idx = (bid - 1152) * 256 + tid;        // < 32768 : packed-4 transpose of lwih
        int i = idx >> 8, j = idx & 255;
        lwihT[(i >> 2) * 1024 + j * 4 + (i & 3)] = lwih[j * 128 + i];
    } else if (bid < 1344) {
        int idx = (bid - 1280) * 256 + tid;        // < 16384 : packed-4 transpose of lwhh
        int i = idx >> 8, j = idx & 255;
        lwhhT[(i >> 2) * 1024 + j * 4 + (i & 3)] = lwhh[j * 64 + i];
    } else if (bid < 1349) {
        int i = (bid - 1344) * 256 + tid;
        if (i <= NB) {
            int lo = 0, hi = N_NODES;
            while (lo < hi) { int mid = (lo + hi) >> 1; if (batch[mid] < i) lo = mid + 1; else hi = mid; }
            offs[i] = lo;
        }
    } else if (bid < 6349) {
        int w = tid >> 6, j = tid & 63;
        int n = (bid - 1349) * 4 + w;
        float acc = b0[j];
        const float* xr = x + n * IND;
#pragma unroll
        for (int i = 0; i < IND; ++i) acc = fmaf(xr[i], W0[i * 64 + j], acc);
        hbuf[n * 64 + j] = fmaxf(acc, 0.0f);
    } else if (bid < 18849) {
        int w = tid >> 6, j = tid & 63;
        int e = (bid - 6349) * 4 + w;
        if (e < N_EDGES) {
            float acc = be1[j];
            const float* er = ea + e * 6;
#pragma unroll
            for (int i = 0; i < 6; ++i) acc = fmaf(er[i], We1[i * 64 + j], acc);
            re[e * 64 + j] = fmaxf(acc, 0.0f);
        }
    } else {
        int e = (bid - 18849) * 256 + tid;
        if (e < N_EDGES) atomicAdd(&deg[ei[N_EDGES + e]], 1);
    }
}

__global__ void k_scan(const int* __restrict__ deg, int* __restrict__ rowptr, int* __restrict__ cursor) {
    __shared__ int s_w[16];
    int t = threadIdx.x;
    int base = t * 20;
    int v[20]; int s = 0;
#pragma unroll
    for (int i = 0; i < 20; ++i) {
        int idx = base + i;
        v[i] = (idx < N_NODES) ? deg[idx] : 0;
        s += v[i];
    }
    int lane = t & 63, w = t >> 6;
    int inc = s;
#pragma unroll
    for (int off = 1; off < 64; off <<= 1) {
        int o = __shfl_up(inc, off);
        if (lane >= off) inc += o;
    }
    if (lane == 63) s_w[w] = inc;
    __syncthreads();
    if (w == 0 && lane < 16) {
        int x = s_w[lane];
        int xs = x;
#pragma unroll
        for (int off = 1; off < 16; off <<= 1) {
            int o = __shfl_up(xs, off);
            if (lane >= off) xs += o;
        }
        s_w[lane] = xs - x;
    }
    __syncthreads();
    int run = s_w[w] + (inc - s);
#pragma unroll
    for (int i = 0; i < 20; ++i) {
        int idx = base + i;
        if (idx < N_NODES) { rowptr[idx] = run; cursor[idx] = run; }
        else if (idx == N_NODES) rowptr[idx] = run;
        run += v[i];
    }
}

__global__ void k_fill(const int* __restrict__ ei, int* __restrict__ cursor, int* __restrict__ perm) {
    int e = blockIdx.x * 256 + threadIdx.x;
    if (e < N_EDGES) {
        int pos = atomicAdd(&cursor[ei[N_EDGES + e]], 1);
        perm[pos] = e;
    }
}

// One step's compute, TRANSPOSED orientation: C'[o][e] = W^T * re^T, so the per-slab
// v-scale is a per-lane scalar (col = lane&15 = edge). 8 MFMA + 16 fmaf.
#define MSG_STEP_COMPUTE(BB0, BB1, PP)                                                              \
    _Pragma("unroll")                                                                               \
    for (int m = 0; m < 4; ++m) {                                                                   \
        f32x4 tt = __builtin_amdgcn_mfma_f32_16x16x32_bf16(BB0.v, a_re[m][0].v, zero4, 0, 0, 0);    \
        tt = __builtin_amdgcn_mfma_f32_16x16x32_bf16(BB1.v, a_re[m][1].v, tt, 0, 0, 0);             \
        macc[m][0] = fmaf(vsc[PP][m], tt[0], macc[m][0]);                                           \
        macc[m][1] = fmaf(vsc[PP][m], tt[1], macc[m][1]);                                           \
        macc[m][2] = fmaf(vsc[PP][m], tt[2], macc[m][2]);                                           \
        macc[m][3] = fmaf(vsc[PP][m], tt[3], macc[m][3]);                                           \
    }

// msg kernel — R2-EXACT (measured 46.6 us): transposed MFMA, register-rotated W
// prefetch, no in-loop barriers, 64 edges/block, 4 waves, full TLP. R4-R7 established
// this sits on the per-CU L2-delivery cap (~15.5 B/cyc x 1.6 MB/CU W-stream) and every
// traffic-reducing restructure lost more to serialization than it gained in bytes.
__launch_bounds__(256, 4)
__global__ void k_msg_mfma(const float* __restrict__ hbuf, const float* __restrict__ reb,
                           const short* __restrict__ We2b, const int* __restrict__ ei,
                           float* __restrict__ msg) {
    __shared__ union {
        float v[64][64];     // [h][e] during the loop + bias
        float out[64][68];   // [e][o] for the coalescing store (padded: 68)
    } s_u;
    int tid = threadIdx.x;
    int eb = blockIdx.x * 64;
    int lane = tid & 63;
    int w = tid >> 6;
    int l15 = lane & 15, lhi = lane >> 4;

    // stage s_v transposed
    {
        int se = tid >> 2;
        int sh = tid & 3;
        int ge = eb + se;
        const float* rowp = (ge < N_EDGES) ? (hbuf + (size_t)ei[ge] * 64) : (const float*)0;
#pragma unroll
        for (int rr4 = 0; rr4 < 4; ++rr4) {
            int hb = rr4 * 16 + sh * 4;
            float4 vv = rowp ? *(const float4*)(rowp + hb) : make_float4(0.f, 0.f, 0.f, 0.f);
            s_u.v[hb + 0][se] = vv.x; s_u.v[hb + 1][se] = vv.y;
            s_u.v[hb + 2][se] = vv.z; s_u.v[hb + 3][se] = vv.w;
        }
    }

    // pack re fragments once (used as the B operand: B[k][col=e])
    union U { int4 i4; bf16x8 v; };
    U a_re[4][2];
#pragma unroll
    for (int m = 0; m < 4; ++m) {
        int ge = eb + m * 16 + l15;
        if (ge < N_EDGES) {
            const float* rp = reb + (size_t)ge * 64 + lhi * 8;
            float4 x0 = *(const float4*)(rp);
            float4 x1 = *(const float4*)(rp + 4);
            float4 y0 = *(const float4*)(rp + 32);
            float4 y1 = *(const float4*)(rp + 36);
            a_re[m][0].i4 = make_int4(pk2(x0.x, x0.y), pk2(x0.z, x0.w), pk2(x1.x, x1.y), pk2(x1.z, x1.w));
            a_re[m][1].i4 = make_int4(pk2(y0.x, y0.y), pk2(y0.z, y0.w), pk2(y1.x, y1.y), pk2(y1.z, y1.w));
        } else {
            a_re[m][0].i4 = make_int4(0, 0, 0, 0);
            a_re[m][1].i4 = make_int4(0, 0, 0, 0);
        }
    }

    // W prefetch (A operand): 4 rotating register sets, depth 4
    const int4* bp0 = (const int4*)We2b + (w * 128 + lane);   // slab stride = 512 int4
    const int4* bp1 = bp0 + 64;
    int4 Sc0[4], Sc1[4];
#pragma unroll
    for (int j = 0; j < 4; ++j) {
        Sc0[j] = bp0[j * 512];
        Sc1[j] = bp1[j * 512];
    }

    __syncthreads();

    const f32x4 zero4 = {0.f, 0.f, 0.f, 0.f};
    f32x4 macc[4];
#pragma unroll
    for (int m = 0; m < 4; ++m) macc[m] = zero4;

    // per-lane v scalars, parity double-buffered (1 step ahead)
    float vsc[2][4];
#pragma unroll
    for (int m = 0; m < 4; ++m) vsc[0][m] = s_u.v[0][m * 16 + l15];

    for (int g = 0; g < 16; ++g) {
#pragma unroll
        for (int j = 0; j < 4; ++j) {
            const int p = j & 1, q = p ^ 1;
            int s = g * 4 + j;
            int snext = (s < 63) ? (s + 1) : 63;
#pragma unroll
            for (int m = 0; m < 4; ++m) vsc[q][m] = s_u.v[snext][m * 16 + l15];
            U bb0, bb1; bb0.i4 = Sc0[j]; bb1.i4 = Sc1[j];
            MSG_STEP_COMPUTE(bb0, bb1, p)
            int sload = (s + 4 <= 64) ? (s + 4) : 64;
            Sc0[j] = bp0[sload * 512];
            Sc1[j] = bp1[sload * 512];
        }
    }

    // bias slab (set 0 holds slab 64): msg^T += be2^T @ v^T
    {
        U bb0, bb1; bb0.i4 = Sc0[0]; bb1.i4 = Sc1[0];
#pragma unroll
        for (int m = 0; m < 4; ++m) {
            int e = m * 16 + l15;
            U a0, a1;
            a0.i4 = make_int4(
                pk2(s_u.v[lhi * 8 + 0][e], s_u.v[lhi * 8 + 1][e]),
                pk2(s_u.v[lhi * 8 + 2][e], s_u.v[lhi * 8 + 3][e]),
                pk2(s_u.v[lhi * 8 + 4][e], s_u.v[lhi * 8 + 5][e]),
                pk2(s_u.v[lhi * 8 + 6][e], s_u.v[lhi * 8 + 7][e]));
            a1.i4 = make_int4(
                pk2(s_u.v[32 + lhi * 8 + 0][e], s_u.v[32 + lhi * 8 + 1][e]),
                pk2(s_u.v[32 + lhi * 8 + 2][e], s_u.v[32 + lhi * 8 + 3][e]),
                pk2(s_u.v[32 + lhi * 8 + 4][e], s_u.v[32 + lhi * 8 + 5][e]),
                pk2(s_u.v[32 + lhi * 8 + 6][e], s_u.v[32 + lhi * 8 + 7][e]));
            macc[m] = __builtin_amdgcn_mfma_f32_16x16x32_bf16(bb0.v, a0.v, macc[m], 0, 0, 0);
            macc[m] = __builtin_amdgcn_mfma_f32_16x16x32_bf16(bb1.v, a1.v, macc[m], 0, 0, 0);
        }
    }

    // transpose through LDS: macc holds C'[o][e]; emit msg[e][o] coalesced
    __syncthreads();   // all waves done reading s_u.v
#pragma unroll
    for (int m = 0; m < 4; ++m) {
        // lane (lhi,l15) holds rows o = w*16+lhi*4+0..3, col e = m*16+l15
        *(float4*)&s_u.out[m * 16 + l15][w * 16 + lhi * 4] =
            make_float4(macc[m][0], macc[m][1], macc[m][2], macc[m][3]);
    }
    __syncthreads();
    {
        int er = tid >> 2, qc = tid & 3;
        int ge = eb + er;
        if (ge < N_EDGES) {
#pragma unroll
            for (int i = 0; i < 4; ++i)
                *(float4*)&msg[(size_t)ge * 64 + qc * 16 + i * 4] =
                    *(const float4*)&s_u.out[er][qc * 16 + i * 4];
        }
    }
}

// MFMA node update: conv + GRU with split-bf16 weights. 32 nodes / block (625 blocks).
__launch_bounds__(256, 4)
__global__ void k_node_update(float* __restrict__ hbuf, const float* __restrict__ msg,
                              const int* __restrict__ rowptr, const int* __restrict__ perm,
                              const short* __restrict__ WB1h, const short* __restrict__ WB1l,
                              const short* __restrict__ WB2h, const short* __restrict__ WB2l,
                              const float* __restrict__ bconv, const float* __restrict__ bih,
                              const float* __restrict__ bhh) {
    __shared__ short s_hh[32][72];
    __shared__ short s_hl[32][72];
    __shared__ short s_mh[32][72];
    __shared__ short s_ml[32][72];
    __shared__ float s_agg[32][68];
    int tid = threadIdx.x;
    int nbase = blockIdx.x * 32;
    int lane = tid & 63, w = tid >> 6;
    int l15 = lane & 15, lhi = lane >> 4;

    {
        int nt = tid >> 3, q = tid & 7;
        int n = nbase + nt;
#pragma unroll
        for (int c4 = 0; c4 < 2; ++c4) {
            int col = q * 8 + c4 * 4;
            float4 v = *(const float4*)&hbuf[(size_t)n * 64 + col];
            unsigned h01 = pk2(v.x, v.y), h23 = pk2(v.z, v.w);
            float f0 = __uint_as_float(h01 << 16);
            float f1 = __uint_as_float(h01 & 0xffff0000u);
            float f2 = __uint_as_float(h23 << 16);
            float f3 = __uint_as_float(h23 & 0xffff0000u);
            unsigned l01 = pk2(v.x - f0, v.y - f1), l23 = pk2(v.z - f2, v.w - f3);
            *(unsigned*)&s_hh[nt][col]     = h01;
            *(unsigned*)&s_hh[nt][col + 2] = h23;
            *(unsigned*)&s_hl[nt][col]     = l01;
            *(unsigned*)&s_hl[nt][col + 2] = l23;
        }
        float4 aggv[2];
#pragma unroll
        for (int c4 = 0; c4 < 2; ++c4)
            aggv[c4] = *(const float4*)&bconv[q * 8 + c4 * 4];
        int rs = rowptr[n], rend = rowptr[n + 1];
        for (int qq = rs; qq < rend; ++qq) {
            const float* mrow = msg + (size_t)perm[qq] * 64 + q * 8;
#pragma unroll
            for (int c4 = 0; c4 < 2; ++c4) {
                float4 mv = *(const float4*)&mrow[c4 * 4];
                aggv[c4].x += mv.x; aggv[c4].y += mv.y;
                aggv[c4].z += mv.z; aggv[c4].w += mv.w;
            }
        }
#pragma unroll
        for (int c4 = 0; c4 < 2; ++c4)
            *(float4*)&s_agg[nt][q * 8 + c4 * 4] = aggv[c4];
    }
    __syncthreads();

    union U { int4 i4; bf16x8 v; };
    U ah[2][2], al[2][2];
#pragma unroll
    for (int m = 0; m < 2; ++m)
#pragma unroll
        for (int c = 0; c < 2; ++c) {
            ah[m][c].i4 = *(const int4*)&s_hh[m * 16 + l15][c * 32 + lhi * 8];
            al[m][c].i4 = *(const int4*)&s_hl[m * 16 + l15][c * 32 + lhi * 8];
        }

    const int4* B1h = (const int4*)WB1h;
    const int4* B1l = (const int4*)WB1l;
    const int4* B2h = (const int4*)WB2h;
    const int4* B2l = (const int4*)WB2l;

    f32x4 C0[2], G[3][2], I[3][2];

    {
        int ot = w;
        U bh0, bh1, bl0, bl1;
        bh0.i4 = B1h[(ot * 2 + 0) * 64 + lane];
        bh1.i4 = B1h[(ot * 2 + 1) * 64 + lane];
        bl0.i4 = B1l[(ot * 2 + 0) * 64 + lane];
        bl1.i4 = B1l[(ot * 2 + 1) * 64 + lane];
#pragma unroll
        for (int m = 0; m < 2; ++m) {
            f32x4 c;
#pragma unroll
            for (int r = 0; r < 4; ++r) c[r] = s_agg[m * 16 + lhi * 4 + r][w * 16 + l15];
            c = __builtin_amdgcn_mfma_f32_16x16x32_bf16(ah[m][0].v, bh0.v, c, 0, 0, 0);
            c = __builtin_amdgcn_mfma_f32_16x16x32_bf16(ah[m][1].v, bh1.v, c, 0, 0, 0);
            c = __builtin_amdgcn_mfma_f32_16x16x32_bf16(al[m][0].v, bh0.v, c, 0, 0, 0);
            c = __builtin_amdgcn_mfma_f32_16x16x32_bf16(al[m][1].v, bh1.v, c, 0, 0, 0);
            c = __builtin_amdgcn_mfma_f32_16x16x32_bf16(ah[m][0].v, bl0.v, c, 0, 0, 0);
            c = __builtin_amdgcn_mfma_f32_16x16x32_bf16(ah[m][1].v, bl1.v, c, 0, 0, 0);
            C0[m] = c;
        }
    }
#pragma unroll
    for (int m = 0; m < 2; ++m)
#pragma unroll
        for (int r = 0; r < 4; ++r) {
            float mv = fmaxf(C0[m][r], 0.0f);
            int row = m * 16 + lhi * 4 + r, col = w * 16 + l15;
            unsigned hs = bf1(mv);
            float lof = mv - __uint_as_float(hs << 16);
            s_mh[row][col] = (short)hs;
            s_ml[row][col] = (short)bf1(lof);
        }
#pragma unroll
    for (int p = 1; p < 4; ++p) {
        int ot = p * 4 + w;
        U bh0, bh1, bl0, bl1;
        bh0.i4 = B1h[(ot * 2 + 0) * 64 + lane];
        bh1.i4 = B1h[(ot * 2 + 1) * 64 + lane];
        bl0.i4 = B1l[(ot * 2 + 0) * 64 + lane];
        bl1.i4 = B1l[(ot * 2 + 1) * 64 + lane];
        float bv = bhh[(p - 1) * 64 + w * 16 + l15];
#pragma unroll
        for (int m = 0; m < 2; ++m) {
            f32x4 c = {bv, bv, bv, bv};
            c = __builtin_amdgcn_mfma_f32_16x16x32_bf16(ah[m][0].v, bh0.v, c, 0, 0, 0);
            c = __builtin_amdgcn_mfma_f32_16x16x32_bf16(ah[m][1].v, bh1.v, c, 0, 0, 0);
            c = __builtin_amdgcn_mfma_f32_16x16x32_bf16(al[m][0].v, bh0.v, c, 0, 0, 0);
            c = __builtin_amdgcn_mfma_f32_16x16x32_bf16(al[m][1].v, bh1.v, c, 0, 0, 0);
            c = __builtin_amdgcn_mfma_f32_16x16x32_bf16(ah[m][0].v, bl0.v, c, 0, 0, 0);
            c = __builtin_amdgcn_mfma_f32_16x16x32_bf16(ah[m][1].v, bl1.v, c, 0, 0, 0);
            G[p - 1][m] = c;
        }
    }
    __syncthreads();
    U mh[2][2], ml[2][2];
#pragma unroll
    for (int m = 0; m < 2; ++m)
#pragma unroll
        for (int c = 0; c < 2; ++c) {
            mh[m][c].i4 = *(const int4*)&s_mh[m * 16 + l15][c * 32 + lhi * 8];
            ml[m][c].i4 = *(const int4*)&s_ml[m * 16 + l15][c * 32 + lhi * 8];
        }
#pragma unroll
    for (int p = 0; p < 3; ++p) {
        int ot = p * 4 + w;
        U bh0, bh1, bl0, bl1;
        bh0.i4 = B2h[(ot * 2 + 0) * 64 + lane];
        bh1.i4 = B2h[(ot * 2 + 1) * 64 + lane];
        bl0.i4 = B2l[(ot * 2 + 0) * 64 + lane];
        bl1.i4 = B2l[(ot * 2 + 1) * 64 + lane];
        float bv = bih[p * 64 + w * 16 + l15];
#pragma unroll
        for (int m = 0; m < 2; ++m) {
            f32x4 c = {bv, bv, bv, bv};
            c = __builtin_amdgcn_mfma_f32_16x16x32_bf16(mh[m][0].v, bh0.v, c, 0, 0, 0);
            c = __builtin_amdgcn_mfma_f32_16x16x32_bf16(mh[m][1].v, bh1.v, c, 0, 0, 0);
            c = __builtin_amdgcn_mfma_f32_16x16x32_bf16(ml[m][0].v, bh0.v, c, 0, 0, 0);
            c = __builtin_amdgcn_mfma_f32_16x16x32_bf16(ml[m][1].v, bh1.v, c, 0, 0, 0);
            c = __builtin_amdgcn_mfma_f32_16x16x32_bf16(mh[m][0].v, bl0.v, c, 0, 0, 0);
            c = __builtin_amdgcn_mfma_f32_16x16x32_bf16(mh[m][1].v, bl1.v, c, 0, 0, 0);
            I[p][m] = c;
        }
    }
#pragma unroll
    for (int m = 0; m < 2; ++m)
#pragma unroll
        for (int r = 0; r < 4; ++r) {
            int row = m * 16 + lhi * 4 + r;
            int n = nbase + row;
            int col = w * 16 + l15;
            float hold = __uint_as_float(((unsigned)(unsigned short)s_hh[row][col]) << 16)
                       + __uint_as_float(((unsigned)(unsigned short)s_hl[row][col]) << 16);
            float rg = sigmoidf_(I[0][m][r] + G[0][m][r]);
            float z  = sigmoidf_(I[1][m][r] + G[1][m][r]);
            float nn = tanhf_(I[2][m][r] + rg * G[2][m][r]);
            hbuf[(size_t)n * 64 + col] = (1.0f - z) * nn + z * hold;
        }
}

// Fused Set2Set (3 iterations) + readout MLP — R2 structure (1024 blocks, 4 waves/graph;
// the R8 4-graph merge was latency-bound at 4x less occupancy) with PACKED-4 weights:
// the matvec was 192 serial scalar dword loads/thread/iter (stride-256 columns); the
// packed layout makes it 48 coalesced dwordx4 loads (16 B/lane), same fp32 math/order.
__launch_bounds__(256)
__global__ void k_set2set(const float* __restrict__ hbuf, const int* __restrict__ offs,
                          const float* __restrict__ t, const float* __restrict__ p,
                          const float* __restrict__ lwihT, const float* __restrict__ lwhhT,
                          const float* __restrict__ l_bih, const float* __restrict__ l_bhh,
                          const float* __restrict__ W1, const float* __restrict__ b1,
                          const float* __restrict__ W2, const float* __restrict__ b2,
                          const float* __restrict__ W3, const float* __restrict__ b3,
                          float* __restrict__ y) {
    __shared__ float s_qs[192];       // [0..127]=q_star, [128..191]=qh
    __shared__ float s_g[256];
    __shared__ float s_racc[4][64];
    __shared__ float s_m[4], s_l[4];
    __shared__ float s_y[64];
    int b = blockIdx.x;
    int tid = threadIdx.x;
    int w = tid >> 6, lane = tid & 63;
    int s = offs[b], e = offs[b + 1];
    float bi = l_bih[tid] + l_bhh[tid];
    float qc = 0.f;                   // live in wave-0 lanes

    if (tid < 192) s_qs[tid] = 0.f;
    __syncthreads();

    const float4* wih4 = (const float4*)lwihT + tid;   // [i4][gate]: stride 256 float4
    const float4* whh4 = (const float4*)lwhhT + tid;

    for (int iter = 0; iter < 3; ++iter) {
        float g = bi;
#pragma unroll 8
        for (int i4 = 0; i4 < 32; ++i4) {
            float4 wv = wih4[i4 * 256];
            g = fmaf(s_qs[i4 * 4 + 0], wv.x, g);
            g = fmaf(s_qs[i4 * 4 + 1], wv.y, g);
            g = fmaf(s_qs[i4 * 4 + 2], wv.z, g);
            g = fmaf(s_qs[i4 * 4 + 3], wv.w, g);
        }
#pragma unroll 8
        for (int i4 = 0; i4 < 16; ++i4) {
            float4 wv = whh4[i4 * 256];
            g = fmaf(s_qs[128 + i4 * 4 + 0], wv.x, g);
            g = fmaf(s_qs[128 + i4 * 4 + 1], wv.y, g);
            g = fmaf(s_qs[128 + i4 * 4 + 2], wv.z, g);
            g = fmaf(s_qs[128 + i4 * 4 + 3], wv.w, g);
        }
        s_g[tid] = g;
        __syncthreads();
        if (w == 0) {
            float ci = sigmoidf_(s_g[lane]);
            float cf = sigmoidf_(s_g[64 + lane]);
            float cg = tanhf_(s_g[128 + lane]);
            float co = sigmoidf_(s_g[192 + lane]);
            qc = cf * qc + ci * cg;
            float qh = co * tanhf_(qc);
            s_qs[lane] = qh;
            s_qs[128 + lane] = qh;
        }
        __syncthreads();
        float qv = s_qs[128 + lane];
        float mx = -1e30f, l = 0.0f, racc = 0.0f;
        for (int n = s + w; n < e; n += 4) {
            float xv = hbuf[(size_t)n * 64 + lane];
            float prod = xv * qv;
#pragma unroll
            for (int off = 32; off > 0; off >>= 1) prod += __shfl_xor(prod, off);
            float mnew = fmaxf(mx, prod);
            float scale = __expf(mx - mnew);
            float wgt = __expf(prod - mnew);
            l = l * scale + wgt;
            racc = racc * scale + wgt * xv;
            mx = mnew;
        }
        s_racc[w][lane] = racc;
        if (lane == 0) { s_m[w] = mx; s_l[w] = l; }
        __syncthreads();
        if (w == 0) {
            float M = fmaxf(fmaxf(s_m[0], s_m[1]), fmaxf(s_m[2], s_m[3]));
            float L = 0.f, R = 0.f;
#pragma unroll
            for (int ww = 0; ww < 4; ++ww) {
                float sc = __expf(s_m[ww] - M);
                L += s_l[ww] * sc;
                R = fmaf(s_racc[ww][lane], sc, R);
            }
            s_qs[64 + lane] = (e > s) ? (R / L) : 0.0f;
        }
        __syncthreads();
    }
    if (w == 0) {
        float acc = b1[lane];
#pragma unroll 8
        for (int i = 0; i < 128; ++i) acc = fmaf(s_qs[i], W1[i * 64 + lane], acc);
        acc = fmaf(t[b], W1[128 * 64 + lane], acc);
        acc = fmaf(p[b], W1[129 * 64 + lane], acc);
        acc = fmaxf(acc, 0.0f);
        s_y[lane] = acc;
        float acc2 = b2[lane];
#pragma unroll 8
        for (int i = 0; i < 64; ++i) acc2 = fmaf(s_y[i], W2[i * 64 + lane], acc2);
        acc2 = fmaxf(acc2, 0.0f);
        float part = acc2 * W3[lane];
#pragma unroll
        for (int off = 32; off > 0; off >>= 1) part += __shfl_xor(part, off);
        if (lane == 0) y[b] = part + b3[0];
    }
}

extern "C" void kernel_launch(void* const* d_in, const int* in_sizes, int n_in,
                              void* d_out, int out_size, void* d_ws, size_t ws_size,
                              hipStream_t stream) {
    const float* x     = (const float*)d_in[0];
    const int*   ei    = (const int*)  d_in[1];
    const float* ea    = (const float*)d_in[2];
    const int*   batch = (const int*)  d_in[3];
    const float* t     = (const float*)d_in[4];
    const float* p     = (const float*)d_in[5];
    const float* W0    = (const float*)d_in[7];
    const float* b0    = (const float*)d_in[8];
    const float* We1   = (const float*)d_in[9];
    const float* be1   = (const float*)d_in[10];
    const float* We2   = (const float*)d_in[11];
    const float* be2   = (const float*)d_in[12];
    const float* Wroot = (const float*)d_in[13];
    const float* bconv = (const float*)d_in[14];
    const float* gwih  = (const float*)d_in[15];
    const float* gwhh  = (const float*)d_in[16];
    const float* gbih  = (const float*)d_in[17];
    const float* gbhh  = (const float*)d_in[18];
    const float* lwih  = (const float*)d_in[19];
    const float* lwhh  = (const float*)d_in[20];
    const float* lbih  = (const float*)d_in[21];
    const float* lbhh  = (const float*)d_in[22];
    const float* W1    = (const float*)d_in[23];
    const float* b1    = (const float*)d_in[24];
    const float* W2    = (const float*)d_in[25];
    const float* b2    = (const float*)d_in[26];
    const float* W3    = (const float*)d_in[27];
    const float* b3    = (const float*)d_in[28];
    float* y = (float*)d_out;

    char* ws = (char*)d_ws;
    size_t off = 0;
    auto alloc = [&](size_t nbytes) {
        void* ptr = (void*)(ws + off);
        off += align_up(nbytes, 256);
        return ptr;
    };
    float* hbuf   = (float*)alloc((size_t)N_NODES * 64 * 4);
    float* reb    = (float*)alloc((size_t)N_EDGES * 64 * 4);
    float* msg    = (float*)alloc((size_t)N_EDGES * 64 * 4);
    short* We2b   = (short*)alloc((size_t)65 * 4096 * 2);
    short* WB1h   = (short*)alloc(16384 * 2);
    short* WB1l   = (short*)alloc(16384 * 2);
    short* WB2h   = (short*)alloc(12288 * 2);
    short* WB2l   = (short*)alloc(12288 * 2);
    float* lwihT  = (float*)alloc(32768 * 4);
    float* lwhhT  = (float*)alloc(16384 * 4);
    int*   offs   = (int*)  alloc((NB + 1) * 4);
    int*   deg    = (int*)  alloc(N_NODES * 4);
    int*   rowptr = (int*)  alloc((N_NODES + 1) * 4);
    int*   cursor = (int*)  alloc(N_NODES * 4);
    int*   perm   = (int*)  alloc(N_EDGES * 4);

    // ---- deg zero FIRST (stream-ordered before k_prep's count blocks) ----
    hipMemsetAsync(deg, 0, (size_t)N_NODES * 4, stream);
    // ---- mega-prep (prep + encoder + edge count) + CSR scan/fill ----
    k_prep<<<19045, 256, 0, stream>>>(We2, be2, We2b, Wroot, gwhh, gwih,
                                      WB1h, WB1l, WB2h, WB2l,
                                      lwih, lwhh, lwihT, lwhhT, batch, offs,
                                      x, W0, b0, hbuf, ea, We1, be1, reb,
                                      ei, deg);
    k_scan<<<1, 1024, 0, stream>>>(deg, rowptr, cursor);
    k_fill<<<(N_EDGES + 255) / 256, 256, 0, stream>>>(ei, cursor, perm);

    // ---- 4 message-passing + GRU iterations ----
    for (int it = 0; it < 4; ++it) {
        k_msg_mfma<<<(N_EDGES + 63) / 64, 256, 0, stream>>>(hbuf, reb, We2b, ei, msg);
        k_node_update<<<N_NODES / 32, 256, 0, stream>>>(hbuf, msg, rowptr, perm,
                                                        WB1h, WB1l, WB2h, WB2l,
                                                        bconv, gbih, gbhh);
    }

    // ---- fused Set2Set (3 iters) + readout ----
    k_set2set<<<NB, 256, 0, stream>>>(hbuf, offs, t, p, lwihT, lwhhT, lbih, lbhh,
                                      W1, b1, W2, b2, W3, b3, y);
}